// Round 3
// baseline (103.435 us; speedup 1.0000x reference)
//
#include <hip/hip_runtime.h>
#include <stdint.h>

typedef unsigned short ushort_t;
typedef __attribute__((ext_vector_type(8))) short bf16x8;
typedef __attribute__((ext_vector_type(4))) float f32x4;
typedef __attribute__((ext_vector_type(8))) unsigned short u16x8;

#define NROW 4096
#define DDIM 512
#define NTOT 8192

// ---------------- ws layout (bytes) ----------------
#define WB_OFF   0u          // bf16[4096*512] Wb 4 MiB
#define GB_OFF   4194304u    // Gb 4 MiB
#define SQBW_OFF 8388608u    // float[4096]
#define SQBG_OFF 8404992u    // float[4096]
#define U_OFF    8421376u    // double[4096]  (zeroed)
#define V_OFF    8454144u    // double[4096]  (zeroed)
#define S_OFF    8486912u    // float[512]    (zeroed)
#define SC_OFF   8488960u    // sc[1]=P dbl, (float*)(sc+2)=scale (zeroed)
#define SSP_OFF  8489088u    // double[256] sumsq partials (zeroed)
#define ZERO_END (SSP_OFF + 2048u)

__device__ __forceinline__ void atomAddF64(double* p, double v) {
  __hip_atomic_fetch_add(p, v, __ATOMIC_RELAXED, __HIP_MEMORY_SCOPE_AGENT);
}
__device__ __forceinline__ void atomAddF32(float* p, float v) {
  __hip_atomic_fetch_add(p, v, __ATOMIC_RELAXED, __HIP_MEMORY_SCOPE_AGENT);
}

__device__ __forceinline__ unsigned short f2bf(float f) {
  unsigned int uu = __float_as_uint(f);
  uu = uu + 0x7FFFu + ((uu >> 16) & 1u);  // RNE
  return (unsigned short)(uu >> 16);
}
__device__ __forceinline__ float bf2f(unsigned short h) {
  return __uint_as_float(((unsigned int)h) << 16);
}

__device__ __forceinline__ void gload16(const void* g, void* l) {
  __builtin_amdgcn_global_load_lds(
      (const __attribute__((address_space(1))) unsigned int*)g,
      (__attribute__((address_space(3))) unsigned int*)l, 16, 0, 0);
}

// ---- prep: fp32 -> bf16, per-row bf16-consistent sumsq; fp32 sumsq -> 256 partial slots
__global__ __launch_bounds__(256) void prep_rows(
    const float* __restrict__ W, const float* __restrict__ G,
    ushort_t* __restrict__ Wb, ushort_t* __restrict__ Gb,
    float* __restrict__ sqbW, float* __restrict__ sqbG,
    double* __restrict__ ssp)
{
  const int row = blockIdx.x * 4 + (threadIdx.x >> 6);  // 0..8191
  const int l = threadIdx.x & 63;
  const float* src; ushort_t* dst; float* sqb; int r;
  if (row < NROW) { src = W + (size_t)row * DDIM; dst = Wb + (size_t)row * DDIM; sqb = sqbW; r = row; }
  else            { src = G + (size_t)(row - NROW) * DDIM; dst = Gb + (size_t)(row - NROW) * DDIM; sqb = sqbG; r = row - NROW; }
  const f32x4 a = *(const f32x4*)(src + l * 8);
  const f32x4 b = *(const f32x4*)(src + l * 8 + 4);
  float s32 = 0.f, sb = 0.f;
  u16x8 h;
  #pragma unroll
  for (int j = 0; j < 4; ++j) {
    float x = a[j]; unsigned short q = f2bf(x); h[j] = q;
    float xb = bf2f(q); s32 += x * x; sb += xb * xb;
  }
  #pragma unroll
  for (int j = 0; j < 4; ++j) {
    float x = b[j]; unsigned short q = f2bf(x); h[4 + j] = q;
    float xb = bf2f(q); s32 += x * x; sb += xb * xb;
  }
  *(u16x8*)(dst + l * 8) = h;
  #pragma unroll
  for (int off = 32; off > 0; off >>= 1) { s32 += __shfl_down(s32, off); sb += __shfl_down(sb, off); }
  if (l == 0) { sqb[r] = sb; atomAddF64(&ssp[blockIdx.x & 255], (double)s32); }
}

// ---- column sums of concat(W,G) (fp32)
__global__ __launch_bounds__(256) void colsum(
    const float* __restrict__ W, const float* __restrict__ G, float* __restrict__ s)
{
  const int t = blockIdx.x * 256 + threadIdx.x;  // 0..65535
  const int c = t & 511;
  const int chunk = t >> 9;                      // 0..127 chunks of 64 rows
  const float* src = (chunk < 64) ? (W + (size_t)chunk * 64 * DDIM)
                                  : (G + (size_t)(chunk - 64) * 64 * DDIM);
  float acc = 0.f;
  for (int r = 0; r < 64; ++r) acc += src[(size_t)r * DDIM + c];
  atomAddF32(&s[c], acc);
}

// ---- bandwidth scalar
__global__ __launch_bounds__(256) void bwk(
    const float* __restrict__ s, const double* __restrict__ ssp, float* __restrict__ scale)
{
  __shared__ double red[256], red2[256];
  const int t = threadIdx.x;
  double s2 = 0.0;
  for (int c = t; c < 512; c += 256) { double x = (double)s[c]; s2 += x * x; }
  red[t] = s2;
  red2[t] = ssp[t];
  __syncthreads();
  for (int k = 128; k > 0; k >>= 1) {
    if (t < k) { red[t] += red[t + k]; red2[t] += red2[t + k]; }
    __syncthreads();
  }
  if (t == 0) {
    double sum_d2 = 2.0 * 8192.0 * red2[0] - 2.0 * red[0];
    double bw = sum_d2 / (8192.0 * 8191.0) / 4.0;
    scale[0] = (float)(1.4426950408889634 / (bw * 16.0));
  }
}

// ---- stage one K-step (st) of all four tiles AW|BW|AG|BG into buf (64 KiB)
// linear LDS dest, inverse-XOR-swizzled global source (rule #21 / T2)
__device__ __forceinline__ void stage_tiles(
    const ushort_t* __restrict__ Wb, const ushort_t* __restrict__ Gb,
    int i0, int j0, int st, int tid, char* buf)
{
  #pragma unroll
  for (int q = 0; q < 4; ++q) {
    const int slot = q * 256 + tid;   // 0..1023, 16B each
    const int row = slot >> 3;
    const int sc = slot & 7;
    const int c = sc ^ (row & 7);
    const size_t offA = ((size_t)(i0 + row) * DDIM + st * 64) * 2 + c * 16;
    const size_t offB = ((size_t)(j0 + row) * DDIM + st * 64) * 2 + c * 16;
    gload16((const char*)Wb + offA, buf + slot * 16);            // AW
    gload16((const char*)Wb + offB, buf + 16384 + slot * 16);    // BW
    gload16((const char*)Gb + offA, buf + 32768 + slot * 16);    // AG
    gload16((const char*)Gb + offB, buf + 49152 + slot * 16);    // BG
  }
}

// ---- one K-step of MFMAs for one gram from staged tiles
__device__ __forceinline__ void compute_tile(
    const char* __restrict__ At, const char* __restrict__ Bt,
    int wr, int wc, int lr, int g, f32x4 acc[4][4])
{
  #pragma unroll
  for (int kk = 0; kk < 2; ++kk) {
    bf16x8 a[4], b[4];
    #pragma unroll
    for (int m = 0; m < 4; ++m) {
      const int row = wr * 64 + m * 16 + lr;
      const int c = kk * 4 + g;
      a[m] = *(const bf16x8*)(At + row * 128 + ((c ^ (row & 7)) * 16));
    }
    #pragma unroll
    for (int n = 0; n < 4; ++n) {
      const int row = wc * 64 + n * 16 + lr;
      const int c = kk * 4 + g;
      b[n] = *(const bf16x8*)(Bt + row * 128 + ((c ^ (row & 7)) * 16));
    }
    #pragma unroll
    for (int m = 0; m < 4; ++m)
      #pragma unroll
      for (int n = 0; n < 4; ++n)
        acc[m][n] = __builtin_amdgcn_mfma_f32_16x16x32_bf16(a[m], b[n], acc[m][n], 0, 0, 0);
  }
}

// ---- main fused kernel: upper-tri tiles, 2-phase double-buffered pipeline, both grams
__global__ __launch_bounds__(256, 1) void gram_kernel(
    const ushort_t* __restrict__ Wb, const ushort_t* __restrict__ Gb,
    const float* __restrict__ sqbW, const float* __restrict__ sqbG,
    const float* __restrict__ scale,
    double* __restrict__ u, double* __restrict__ v, double* __restrict__ P)
{
  __shared__ __align__(16) char lds[2][65536];   // [buf][AW|BW|AG|BG]
  __shared__ double pred[4];

  // decode upper-triangular tile index: 0 <= bi <= bj < 32
  int t = blockIdx.x;
  int bi = 0;
  while (t >= 32 - bi) { t -= 32 - bi; ++bi; }
  const int bj = bi + t;
  const bool offdiag = (bi != bj);

  const int tid = threadIdx.x;
  const int lane = tid & 63;
  const int wid = tid >> 6;
  const int wr = wid >> 1;
  const int wc = wid & 1;
  const int i0 = bi * 128;
  const int j0 = bj * 128;
  const int g = lane >> 4;
  const int lr = lane & 15;

  f32x4 accW[4][4], accG[4][4];
  #pragma unroll
  for (int m = 0; m < 4; ++m)
    #pragma unroll
    for (int n = 0; n < 4; ++n) { accW[m][n] = (f32x4)0.0f; accG[m][n] = (f32x4)0.0f; }

  // prologue: stage K-step 0, drain, then 2-phase pipeline (T3 minimum recipe)
  stage_tiles(Wb, Gb, i0, j0, 0, tid, lds[0]);
  __syncthreads();

  int cur = 0;
  for (int st = 0; st < 8; ++st) {
    if (st < 7) stage_tiles(Wb, Gb, i0, j0, st + 1, tid, lds[cur ^ 1]);
    compute_tile(lds[cur], lds[cur] + 16384, wr, wc, lr, g, accW);
    compute_tile(lds[cur] + 32768, lds[cur] + 49152, wr, wc, lr, g, accG);
    __syncthreads();   // implicit vmcnt(0)+lgkmcnt(0): prefetch landed, reads done
    cur ^= 1;
  }

  const float s4 = scale[0];

  float riW[16], riG[16], rjW[4], rjG[4];
  #pragma unroll
  for (int m = 0; m < 4; ++m)
    #pragma unroll
    for (int e = 0; e < 4; ++e) {
      const int i = i0 + wr * 64 + m * 16 + g * 4 + e;
      riW[m * 4 + e] = sqbW[i];
      riG[m * 4 + e] = sqbG[i];
    }
  #pragma unroll
  for (int n = 0; n < 4; ++n) {
    const int j = j0 + wc * 64 + n * 16 + lr;
    rjW[n] = sqbW[j];
    rjG[n] = sqbG[j];
  }

  double p_loc = 0.0;
  float rsW[4][4], rsG[4][4], csW[4], csG[4];
  #pragma unroll
  for (int m = 0; m < 4; ++m)
    #pragma unroll
    for (int e = 0; e < 4; ++e) { rsW[m][e] = 0.f; rsG[m][e] = 0.f; }
  #pragma unroll
  for (int n = 0; n < 4; ++n) { csW[n] = 0.f; csG[n] = 0.f; }

  #pragma unroll
  for (int m = 0; m < 4; ++m) {
    #pragma unroll
    for (int n = 0; n < 4; ++n) {
      #pragma unroll
      for (int e = 0; e < 4; ++e) {
        // K = y + y^2 + y^4 + y^8 + y^16, y = exp(-d2/(16*bw)) : one transcendental
        float d2w = fmaxf(riW[m * 4 + e] + rjW[n] - 2.f * accW[m][n][e], 0.f);
        float yw = exp2f(-d2w * s4);
        float yw2 = yw * yw, yw4 = yw2 * yw2, yw8 = yw4 * yw4, yw16 = yw8 * yw8;
        float kw = yw + yw2 + yw4 + yw8 + yw16;
        float d2g = fmaxf(riG[m * 4 + e] + rjG[n] - 2.f * accG[m][n][e], 0.f);
        float yg = exp2f(-d2g * s4);
        float yg2 = yg * yg, yg4 = yg2 * yg2, yg8 = yg4 * yg4, yg16 = yg8 * yg8;
        float kg = yg + yg2 + yg4 + yg8 + yg16;
        p_loc += (double)(kw * kg);
        rsW[m][e] += kw;
        rsG[m][e] += kg;
        csW[n] += kw;
        csG[n] += kg;
      }
    }
  }

  // row sums (over the tile's j-columns): butterfly across the 16 column-lanes
  #pragma unroll
  for (int m = 0; m < 4; ++m)
    #pragma unroll
    for (int e = 0; e < 4; ++e) {
      float x = rsW[m][e];
      float y = rsG[m][e];
      x += __shfl_xor(x, 1); x += __shfl_xor(x, 2); x += __shfl_xor(x, 4); x += __shfl_xor(x, 8);
      y += __shfl_xor(y, 1); y += __shfl_xor(y, 2); y += __shfl_xor(y, 4); y += __shfl_xor(y, 8);
      if (lr == 0) {
        const int i = i0 + wr * 64 + m * 16 + g * 4 + e;
        atomAddF64(&u[i], (double)x);
        atomAddF64(&v[i], (double)y);
      }
    }

  // off-diagonal: column sums feed the transposed half (K symmetric)
  if (offdiag) {
    #pragma unroll
    for (int n = 0; n < 4; ++n) {
      float x = csW[n];
      float y = csG[n];
      x += __shfl_xor(x, 16); x += __shfl_xor(x, 32);
      y += __shfl_xor(y, 16); y += __shfl_xor(y, 32);
      if (g == 0) {
        const int j = j0 + wc * 64 + n * 16 + lr;
        atomAddF64(&u[j], (double)x);
        atomAddF64(&v[j], (double)y);
      }
    }
  }

  // P: wave butterfly then one atomic per block (off-diag counts twice)
  #pragma unroll
  for (int off = 32; off > 0; off >>= 1) p_loc += __shfl_xor(p_loc, off);
  if (lane == 0) pred[wid] = p_loc;
  __syncthreads();
  if (tid == 0) {
    double ps = pred[0] + pred[1] + pred[2] + pred[3];
    atomAddF64(P, offdiag ? 2.0 * ps : ps);
  }
}

// ---- finalize: loss = -(P - (2/n) u.v + Su*Sv/n^2) / (n-1)^2
__global__ __launch_bounds__(256) void finalize(
    const double* __restrict__ u, const double* __restrict__ v,
    const double* __restrict__ P, float* __restrict__ out)
{
  __shared__ double r0[256], r1[256], r2[256];
  const int t = threadIdx.x;
  double uv = 0.0, su = 0.0, sv = 0.0;
  for (int i = t; i < NROW; i += 256) { double a = u[i], b = v[i]; uv += a * b; su += a; sv += b; }
  r0[t] = uv; r1[t] = su; r2[t] = sv; __syncthreads();
  for (int k = 128; k > 0; k >>= 1) {
    if (t < k) { r0[t] += r0[t + k]; r1[t] += r1[t + k]; r2[t] += r2[t + k]; }
    __syncthreads();
  }
  if (t == 0) {
    const double n = 4096.0;
    double hsic = P[0] - (2.0 / n) * r0[0] + (r1[0] * r2[0]) / (n * n);
    out[0] = (float)(-hsic / ((n - 1.0) * (n - 1.0)));
  }
}

extern "C" void kernel_launch(void* const* d_in, const int* in_sizes, int n_in,
                              void* d_out, int out_size, void* d_ws, size_t ws_size,
                              hipStream_t stream) {
  const float* W = (const float*)d_in[0];
  const float* G = (const float*)d_in[1];
  char* ws = (char*)d_ws;
  ushort_t* Wb = (ushort_t*)(ws + WB_OFF);
  ushort_t* Gb = (ushort_t*)(ws + GB_OFF);
  float* sqbW = (float*)(ws + SQBW_OFF);
  float* sqbG = (float*)(ws + SQBG_OFF);
  double* u = (double*)(ws + U_OFF);
  double* v = (double*)(ws + V_OFF);
  float* s = (float*)(ws + S_OFF);
  double* sc = (double*)(ws + SC_OFF);   // sc[1]=P, (float*)(sc+2)=scale
  double* ssp = (double*)(ws + SSP_OFF); // 256 sumsq partials

  hipMemsetAsync(ws + U_OFF, 0, ZERO_END - U_OFF, stream);

  prep_rows<<<2048, 256, 0, stream>>>(W, G, Wb, Gb, sqbW, sqbG, ssp);
  colsum<<<256, 256, 0, stream>>>(W, G, s);
  bwk<<<1, 256, 0, stream>>>(s, ssp, (float*)(sc + 2));
  gram_kernel<<<528, 256, 0, stream>>>(Wb, Gb, sqbW, sqbG, (const float*)(sc + 2), u, v, &sc[1]);
  finalize<<<1, 256, 0, stream>>>(u, v, &sc[1], (float*)d_out);
}

// Round 4
// 85.719 us; speedup vs baseline: 1.2067x; 1.2067x over previous
//
#include <hip/hip_runtime.h>
#include <stdint.h>

typedef unsigned short ushort_t;
typedef __attribute__((ext_vector_type(8))) short bf16x8;
typedef __attribute__((ext_vector_type(4))) float f32x4;
typedef __attribute__((ext_vector_type(8))) unsigned short u16x8;

#define NROW 4096
#define DDIM 512
#define NPAD 4224          // 22 * 192
#define NT   22            // tiles per dim
#define TS   192

// ---------------- ws layout (bytes) ----------------
#define WB_OFF   0u          // bf16[4224*512] = 4325376
#define GB_OFF   4325376u    // bf16[4224*512]
#define SQBW_OFF 8650752u    // float[4224] = 16896
#define SQBG_OFF 8667648u    // float[4224]
#define U_OFF    8684544u    // double[4224] = 33792 (zeroed)
#define V_OFF    8718336u    // double[4224]          (zeroed)
#define SCS_OFF  8752128u    // float[32][512] = 65536 (zeroed)
#define SSP_OFF  8817664u    // double[256] = 2048     (zeroed)
#define SC_OFF   8819712u    // [0]=P double; (float*)(+8)=scale (zeroed)
#define ZERO_END 8819744u

__device__ __forceinline__ void atomAddF64(double* p, double v) {
  __hip_atomic_fetch_add(p, v, __ATOMIC_RELAXED, __HIP_MEMORY_SCOPE_AGENT);
}
__device__ __forceinline__ void atomAddF32(float* p, float v) {
  __hip_atomic_fetch_add(p, v, __ATOMIC_RELAXED, __HIP_MEMORY_SCOPE_AGENT);
}

__device__ __forceinline__ unsigned short f2bf(float f) {
  unsigned int uu = __float_as_uint(f);
  uu = uu + 0x7FFFu + ((uu >> 16) & 1u);  // RNE
  return (unsigned short)(uu >> 16);
}
__device__ __forceinline__ float bf2f(unsigned short h) {
  return __uint_as_float(((unsigned int)h) << 16);
}

__device__ __forceinline__ void gload16(const void* g, void* l) {
  __builtin_amdgcn_global_load_lds(
      (const __attribute__((address_space(1))) unsigned int*)g,
      (__attribute__((address_space(3))) unsigned int*)l, 16, 0, 0);
}

// ---- prep: fp32->bf16 (+zero pad rows), bf16-consistent row sumsq, fused column sums
__global__ __launch_bounds__(256) void prep_rows(
    const float* __restrict__ W, const float* __restrict__ G,
    ushort_t* __restrict__ Wb, ushort_t* __restrict__ Gb,
    float* __restrict__ sqbW, float* __restrict__ sqbG,
    double* __restrict__ ssp, float* __restrict__ scs)
{
  __shared__ float cols[4][512];
  const int bid = blockIdx.x;
  const int w = threadIdx.x >> 6;
  const int l = threadIdx.x & 63;

  if (bid >= 2048) {                       // pad-row zeroing blocks
    const int pr = (bid - 2048) * 4 + w;   // 0..255
    const bool isG = pr >= 128;
    const int row = NROW + (pr & 127);     // 4096..4223
    ushort_t* dst = (isG ? Gb : Wb) + (size_t)row * DDIM;
    *(f32x4*)(dst + l * 8) = (f32x4)0.0f;  // 16B of zero bf16
    if (l == 0) (isG ? sqbG : sqbW)[row] = 0.f;
    return;
  }

  const int row = bid * 4 + w;             // 0..8191
  const float* src; ushort_t* dst; float* sqb; int r;
  if (row < NROW) { src = W + (size_t)row * DDIM; dst = Wb + (size_t)row * DDIM; sqb = sqbW; r = row; }
  else            { src = G + (size_t)(row - NROW) * DDIM; dst = Gb + (size_t)(row - NROW) * DDIM; sqb = sqbG; r = row - NROW; }
  const f32x4 a = *(const f32x4*)(src + l * 8);
  const f32x4 b = *(const f32x4*)(src + l * 8 + 4);
  float s32 = 0.f, sb = 0.f;
  u16x8 h;
  #pragma unroll
  for (int j = 0; j < 4; ++j) {
    float x = a[j]; unsigned short q = f2bf(x); h[j] = q;
    float xb = bf2f(q); s32 += x * x; sb += xb * xb;
  }
  #pragma unroll
  for (int j = 0; j < 4; ++j) {
    float x = b[j]; unsigned short q = f2bf(x); h[4 + j] = q;
    float xb = bf2f(q); s32 += x * x; sb += xb * xb;
  }
  *(u16x8*)(dst + l * 8) = h;

  // fused column sums (fp32 source values)
  *(f32x4*)&cols[w][l * 8] = a;
  *(f32x4*)&cols[w][l * 8 + 4] = b;
  __syncthreads();
  for (int c = threadIdx.x; c < 512; c += 256)
    atomAddF32(&scs[(bid & 31) * 512 + c],
               cols[0][c] + cols[1][c] + cols[2][c] + cols[3][c]);

  #pragma unroll
  for (int off = 32; off > 0; off >>= 1) { s32 += __shfl_down(s32, off); sb += __shfl_down(sb, off); }
  if (l == 0) { sqb[r] = sb; atomAddF64(&ssp[bid & 255], (double)s32); }
}

// ---- bandwidth scalar from column-sum partials + sumsq partials
__global__ __launch_bounds__(256) void bwk(
    const float* __restrict__ scs, const double* __restrict__ ssp, float* __restrict__ scale)
{
  __shared__ double red[256], red2[256];
  const int t = threadIdx.x;
  double s2 = 0.0;
  for (int c = t; c < 512; c += 256) {
    double cs = 0.0;
    for (int p = 0; p < 32; ++p) cs += (double)scs[p * 512 + c];
    s2 += cs * cs;
  }
  red[t] = s2; red2[t] = ssp[t];
  __syncthreads();
  for (int k = 128; k > 0; k >>= 1) {
    if (t < k) { red[t] += red[t + k]; red2[t] += red2[t + k]; }
    __syncthreads();
  }
  if (t == 0) {
    double sum_d2 = 2.0 * 8192.0 * red2[0] - 2.0 * red[0];
    double bw = sum_d2 / (8192.0 * 8191.0) / 4.0;
    scale[0] = (float)(1.4426950408889634 / (bw * 16.0));
  }
}

// ---- main fused kernel: 192^2 upper-tri tiles, 253 blocks (all co-resident), 8 waves
__global__ __launch_bounds__(512, 2) void gram_kernel(
    const ushort_t* __restrict__ Wb, const ushort_t* __restrict__ Gb,
    const float* __restrict__ sqbW, const float* __restrict__ sqbG,
    const float* __restrict__ scale,
    double* __restrict__ u, double* __restrict__ v, double* __restrict__ P)
{
  __shared__ __align__(16) char lds[4 * 24576];   // AW|BW|AG|BG, 192x64 bf16 each
  __shared__ double pred[8];

  // decode upper-triangular tile index: 0 <= bi <= bj < 22
  int t = blockIdx.x;
  int bi = 0;
  while (t >= NT - bi) { t -= NT - bi; ++bi; }
  const int bj = bi + t;
  const bool offdiag = (bi != bj);

  const int tid = threadIdx.x;
  const int lane = tid & 63;
  const int wid = tid >> 6;
  const int wr = wid >> 2;      // 0..1  (96-row half)
  const int wc = wid & 3;       // 0..3  (48-col quarter)
  const int i0 = bi * TS;
  const int j0 = bj * TS;
  const int g = lane >> 4;
  const int lr = lane & 15;

  char* AW = lds;
  char* BW = lds + 24576;
  char* AG = lds + 49152;
  char* BG = lds + 73728;

  f32x4 accW[6][3], accG[6][3];
  #pragma unroll
  for (int m = 0; m < 6; ++m)
    #pragma unroll
    for (int n = 0; n < 3; ++n) { accW[m][n] = (f32x4)0.0f; accG[m][n] = (f32x4)0.0f; }

  const char* Wb8 = (const char*)Wb;
  const char* Gb8 = (const char*)Gb;

  for (int st = 0; st < 8; ++st) {
    // stage all four 192x64 subtiles; linear LDS dest, inverse-swizzled source (rule #21)
    #pragma unroll
    for (int q = 0; q < 3; ++q) {
      const int slot = q * 512 + tid;    // 0..1535, 16B each
      const int row = slot >> 3;
      const int c = (slot & 7) ^ (row & 7);
      const size_t offA = (size_t)(i0 + row) * 1024 + st * 128 + c * 16;
      const size_t offB = (size_t)(j0 + row) * 1024 + st * 128 + c * 16;
      gload16(Wb8 + offA, AW + slot * 16);
      gload16(Wb8 + offB, BW + slot * 16);
      gload16(Gb8 + offA, AG + slot * 16);
      gload16(Gb8 + offB, BG + slot * 16);
    }
    __syncthreads();

    // W pass
    #pragma unroll
    for (int kk = 0; kk < 2; ++kk) {
      bf16x8 a[6], b[3];
      #pragma unroll
      for (int m = 0; m < 6; ++m) {
        const int row = wr * 96 + m * 16 + lr;
        const int c = kk * 4 + g;
        a[m] = *(const bf16x8*)(AW + row * 128 + ((c ^ (row & 7)) * 16));
      }
      #pragma unroll
      for (int n = 0; n < 3; ++n) {
        const int row = wc * 48 + n * 16 + lr;
        const int c = kk * 4 + g;
        b[n] = *(const bf16x8*)(BW + row * 128 + ((c ^ (row & 7)) * 16));
      }
      #pragma unroll
      for (int m = 0; m < 6; ++m)
        #pragma unroll
        for (int n = 0; n < 3; ++n)
          accW[m][n] = __builtin_amdgcn_mfma_f32_16x16x32_bf16(a[m], b[n], accW[m][n], 0, 0, 0);
    }
    // G pass
    #pragma unroll
    for (int kk = 0; kk < 2; ++kk) {
      bf16x8 a[6], b[3];
      #pragma unroll
      for (int m = 0; m < 6; ++m) {
        const int row = wr * 96 + m * 16 + lr;
        const int c = kk * 4 + g;
        a[m] = *(const bf16x8*)(AG + row * 128 + ((c ^ (row & 7)) * 16));
      }
      #pragma unroll
      for (int n = 0; n < 3; ++n) {
        const int row = wc * 48 + n * 16 + lr;
        const int c = kk * 4 + g;
        b[n] = *(const bf16x8*)(BG + row * 128 + ((c ^ (row & 7)) * 16));
      }
      #pragma unroll
      for (int m = 0; m < 6; ++m)
        #pragma unroll
        for (int n = 0; n < 3; ++n)
          accG[m][n] = __builtin_amdgcn_mfma_f32_16x16x32_bf16(a[m], b[n], accG[m][n], 0, 0, 0);
    }
    __syncthreads();
  }

  // ---- epilogue ----
  const float s4 = scale[0];

  float rjW[3], rjG[3], mjf[3];
  #pragma unroll
  for (int n = 0; n < 3; ++n) {
    const int j = j0 + wc * 48 + n * 16 + lr;
    rjW[n] = sqbW[j]; rjG[n] = sqbG[j];
    mjf[n] = (j < NROW) ? 1.f : 0.f;
  }

  float csW[3] = {0.f, 0.f, 0.f}, csG[3] = {0.f, 0.f, 0.f};
  double p_loc = 0.0;

  #pragma unroll
  for (int m = 0; m < 6; ++m) {
    const int ib = i0 + wr * 96 + m * 16 + g * 4;
    float riW[4], riG[4], mif[4];
    #pragma unroll
    for (int e = 0; e < 4; ++e) {
      riW[e] = sqbW[ib + e]; riG[e] = sqbG[ib + e];
      mif[e] = (ib + e < NROW) ? 1.f : 0.f;
    }
    float rsW[4] = {0.f,0.f,0.f,0.f}, rsG[4] = {0.f,0.f,0.f,0.f};
    #pragma unroll
    for (int n = 0; n < 3; ++n) {
      #pragma unroll
      for (int e = 0; e < 4; ++e) {
        const float mk = mif[e] * mjf[n];
        float d2w = fmaxf(riW[e] + rjW[n] - 2.f * accW[m][n][e], 0.f);
        float yw = exp2f(-d2w * s4);
        float yw2 = yw * yw, yw4 = yw2 * yw2, yw8 = yw4 * yw4, yw16 = yw8 * yw8;
        float kw = (yw + yw2 + yw4 + yw8 + yw16) * mk;
        float d2g = fmaxf(riG[e] + rjG[n] - 2.f * accG[m][n][e], 0.f);
        float yg = exp2f(-d2g * s4);
        float yg2 = yg * yg, yg4 = yg2 * yg2, yg8 = yg4 * yg4, yg16 = yg8 * yg8;
        float kg = (yg + yg2 + yg4 + yg8 + yg16) * mk;
        p_loc += (double)(kw * kg);
        rsW[e] += kw; rsG[e] += kg;
        csW[n] += kw; csG[n] += kg;
      }
    }
    // row sums: butterfly across the 16 column-lanes, one f64 atomic per row
    #pragma unroll
    for (int e = 0; e < 4; ++e) {
      float x = rsW[e], y = rsG[e];
      x += __shfl_xor(x, 1); x += __shfl_xor(x, 2); x += __shfl_xor(x, 4); x += __shfl_xor(x, 8);
      y += __shfl_xor(y, 1); y += __shfl_xor(y, 2); y += __shfl_xor(y, 4); y += __shfl_xor(y, 8);
      if (lr == 0) {
        atomAddF64(&u[ib + e], (double)x);
        atomAddF64(&v[ib + e], (double)y);
      }
    }
  }

  // off-diagonal: column sums feed the transposed half (K symmetric)
  if (offdiag) {
    #pragma unroll
    for (int n = 0; n < 3; ++n) {
      float x = csW[n], y = csG[n];
      x += __shfl_xor(x, 16); x += __shfl_xor(x, 32);
      y += __shfl_xor(y, 16); y += __shfl_xor(y, 32);
      if (g == 0) {
        const int j = j0 + wc * 48 + n * 16 + lr;
        atomAddF64(&u[j], (double)x);
        atomAddF64(&v[j], (double)y);
      }
    }
  }

  // P: wave butterfly then one atomic per block (off-diag counts twice)
  #pragma unroll
  for (int off = 32; off > 0; off >>= 1) p_loc += __shfl_xor(p_loc, off);
  if (lane == 0) pred[wid] = p_loc;
  __syncthreads();
  if (tid == 0) {
    double ps = 0.0;
    #pragma unroll
    for (int k = 0; k < 8; ++k) ps += pred[k];
    atomAddF64(P, offdiag ? 2.0 * ps : ps);
  }
}

// ---- finalize: loss = -(P - (2/n) u.v + Su*Sv/n^2) / (n-1)^2
__global__ __launch_bounds__(256) void finalize(
    const double* __restrict__ u, const double* __restrict__ v,
    const double* __restrict__ P, float* __restrict__ out)
{
  __shared__ double r0[256], r1[256], r2[256];
  const int t = threadIdx.x;
  double uv = 0.0, su = 0.0, sv = 0.0;
  for (int i = t; i < NROW; i += 256) { double a = u[i], b = v[i]; uv += a * b; su += a; sv += b; }
  r0[t] = uv; r1[t] = su; r2[t] = sv; __syncthreads();
  for (int k = 128; k > 0; k >>= 1) {
    if (t < k) { r0[t] += r0[t + k]; r1[t] += r1[t + k]; r2[t] += r2[t + k]; }
    __syncthreads();
  }
  if (t == 0) {
    const double n = 4096.0;
    double hsic = P[0] - (2.0 / n) * r0[0] + (r1[0] * r2[0]) / (n * n);
    out[0] = (float)(-hsic / ((n - 1.0) * (n - 1.0)));
  }
}

extern "C" void kernel_launch(void* const* d_in, const int* in_sizes, int n_in,
                              void* d_out, int out_size, void* d_ws, size_t ws_size,
                              hipStream_t stream) {
  const float* W = (const float*)d_in[0];
  const float* G = (const float*)d_in[1];
  char* ws = (char*)d_ws;
  ushort_t* Wb = (ushort_t*)(ws + WB_OFF);
  ushort_t* Gb = (ushort_t*)(ws + GB_OFF);
  float* sqbW = (float*)(ws + SQBW_OFF);
  float* sqbG = (float*)(ws + SQBG_OFF);
  double* u = (double*)(ws + U_OFF);
  double* v = (double*)(ws + V_OFF);
  float* scs = (float*)(ws + SCS_OFF);
  double* ssp = (double*)(ws + SSP_OFF);
  double* P = (double*)(ws + SC_OFF);
  float* scale = (float*)(ws + SC_OFF + 8);

  hipMemsetAsync(ws + U_OFF, 0, ZERO_END - U_OFF, stream);

  prep_rows<<<2112, 256, 0, stream>>>(W, G, Wb, Gb, sqbW, sqbG, ssp, scs);
  bwk<<<1, 256, 0, stream>>>(scs, ssp, scale);
  gram_kernel<<<253, 512, 0, stream>>>(Wb, Gb, sqbW, sqbG, scale, u, v, P);
  finalize<<<1, 256, 0, stream>>>(u, v, P, (float*)d_out);
}

// Round 5
// 83.759 us; speedup vs baseline: 1.2349x; 1.0234x over previous
//
#include <hip/hip_runtime.h>
#include <stdint.h>

typedef unsigned short ushort_t;
typedef __attribute__((ext_vector_type(8))) short bf16x8;
typedef __attribute__((ext_vector_type(4))) float f32x4;
typedef __attribute__((ext_vector_type(8))) unsigned short u16x8;

#define NROW 4096
#define DDIM 512
#define NPAD 4224          // 22 * 192
#define NT   22            // tiles per dim
#define TS   192

// ---------------- ws layout (bytes) ----------------
#define WB_OFF   0u          // bf16[4224*512] = 4325376
#define GB_OFF   4325376u    // bf16[4224*512]
#define SQBW_OFF 8650752u    // float[4224] = 16896
#define SQBG_OFF 8667648u    // float[4224]
#define U_OFF    8684544u    // double[4224] = 33792 (zeroed)
#define V_OFF    8718336u    // double[4224]          (zeroed)
#define SCS_OFF  8752128u    // float[32][512] = 65536 (zeroed)
#define SSP_OFF  8817664u    // double[256] = 2048     (zeroed)
#define SC_OFF   8819712u    // [0]=P double (zeroed)
#define ZERO_END 8819744u

__device__ __forceinline__ void atomAddF64(double* p, double v) {
  __hip_atomic_fetch_add(p, v, __ATOMIC_RELAXED, __HIP_MEMORY_SCOPE_AGENT);
}
__device__ __forceinline__ void atomAddF32(float* p, float v) {
  __hip_atomic_fetch_add(p, v, __ATOMIC_RELAXED, __HIP_MEMORY_SCOPE_AGENT);
}

__device__ __forceinline__ unsigned short f2bf(float f) {
  unsigned int uu = __float_as_uint(f);
  uu = uu + 0x7FFFu + ((uu >> 16) & 1u);  // RNE
  return (unsigned short)(uu >> 16);
}
__device__ __forceinline__ float bf2f(unsigned short h) {
  return __uint_as_float(((unsigned int)h) << 16);
}

__device__ __forceinline__ void gload16(const void* g, void* l) {
  __builtin_amdgcn_global_load_lds(
      (const __attribute__((address_space(1))) unsigned int*)g,
      (__attribute__((address_space(3))) unsigned int*)l, 16, 0, 0);
}

// ---- prep: fp32->bf16 (+zero pad rows), bf16-consistent row sumsq, fused column sums
__global__ __launch_bounds__(256) void prep_rows(
    const float* __restrict__ W, const float* __restrict__ G,
    ushort_t* __restrict__ Wb, ushort_t* __restrict__ Gb,
    float* __restrict__ sqbW, float* __restrict__ sqbG,
    double* __restrict__ ssp, float* __restrict__ scs)
{
  __shared__ float cols[4][512];
  const int bid = blockIdx.x;
  const int w = threadIdx.x >> 6;
  const int l = threadIdx.x & 63;

  if (bid >= 2048) {                       // pad-row zeroing blocks
    const int pr = (bid - 2048) * 4 + w;   // 0..255
    const bool isG = pr >= 128;
    const int row = NROW + (pr & 127);     // 4096..4223
    ushort_t* dst = (isG ? Gb : Wb) + (size_t)row * DDIM;
    *(f32x4*)(dst + l * 8) = (f32x4)0.0f;  // 16B of zero bf16
    if (l == 0) (isG ? sqbG : sqbW)[row] = 0.f;
    return;
  }

  const int row = bid * 4 + w;             // 0..8191
  const float* src; ushort_t* dst; float* sqb; int r;
  if (row < NROW) { src = W + (size_t)row * DDIM; dst = Wb + (size_t)row * DDIM; sqb = sqbW; r = row; }
  else            { src = G + (size_t)(row - NROW) * DDIM; dst = Gb + (size_t)(row - NROW) * DDIM; sqb = sqbG; r = row - NROW; }
  const f32x4 a = *(const f32x4*)(src + l * 8);
  const f32x4 b = *(const f32x4*)(src + l * 8 + 4);
  float s32 = 0.f, sb = 0.f;
  u16x8 h;
  #pragma unroll
  for (int j = 0; j < 4; ++j) {
    float x = a[j]; unsigned short q = f2bf(x); h[j] = q;
    float xb = bf2f(q); s32 += x * x; sb += xb * xb;
  }
  #pragma unroll
  for (int j = 0; j < 4; ++j) {
    float x = b[j]; unsigned short q = f2bf(x); h[4 + j] = q;
    float xb = bf2f(q); s32 += x * x; sb += xb * xb;
  }
  *(u16x8*)(dst + l * 8) = h;

  // fused column sums (fp32 source values)
  *(f32x4*)&cols[w][l * 8] = a;
  *(f32x4*)&cols[w][l * 8 + 4] = b;
  __syncthreads();
  for (int c = threadIdx.x; c < 512; c += 256)
    atomAddF32(&scs[(bid & 31) * 512 + c],
               cols[0][c] + cols[1][c] + cols[2][c] + cols[3][c]);

  #pragma unroll
  for (int off = 32; off > 0; off >>= 1) { s32 += __shfl_down(s32, off); sb += __shfl_down(sb, off); }
  if (l == 0) { sqb[r] = sb; atomAddF64(&ssp[bid & 255], (double)s32); }
}

// ---- stage one BK=32 K-step: 4 panels AW|BW|AG|BG (192x32 bf16 = 12288 B each)
// LDS linear dest (slot*16); global source column pre-swizzled: c = s ^ ((row>>1)&3)
__device__ __forceinline__ void stage_step(
    const char* __restrict__ Wb8, const char* __restrict__ Gb8,
    int i0, int j0, int st, int tid, char* buf)
{
  const size_t kb = (size_t)st * 64;
  #pragma unroll
  for (int q = 0; q < 6; ++q) {
    const int slot = q * 512 + tid;   // 0..3071
    int p;
    if (q == 0) p = 0;
    else if (q == 1) p = (slot < 768) ? 0 : 1;
    else if (q == 2) p = 1;
    else if (q == 3) p = 2;
    else if (q == 4) p = (slot < 2304) ? 2 : 3;
    else p = 3;
    const char* mat = (p < 2) ? Wb8 : Gb8;
    const int rb = (p & 1) ? j0 : i0;
    const int r = slot - p * 768;
    const int row = r >> 2;
    const int s = r & 3;
    const int c = s ^ ((row >> 1) & 3);
    gload16(mat + (size_t)(rb + row) * 1024 + kb + c * 16, buf + (size_t)slot * 16);
  }
}

// ---- one K=32 step of 18 MFMAs for one gram (A panel at base, B panel at base+12288)
__device__ __forceinline__ void gram_pass(
    const char* __restrict__ base, int wr, int wc, int lr, int g, f32x4 acc[6][3])
{
  bf16x8 a[6], b[3];
  #pragma unroll
  for (int m = 0; m < 6; ++m) {
    const int row = wr * 96 + m * 16 + lr;
    a[m] = *(const bf16x8*)(base + row * 64 + ((g ^ ((row >> 1) & 3)) << 4));
  }
  #pragma unroll
  for (int n = 0; n < 3; ++n) {
    const int row = wc * 48 + n * 16 + lr;
    b[n] = *(const bf16x8*)(base + 12288 + row * 64 + ((g ^ ((row >> 1) & 3)) << 4));
  }
  __builtin_amdgcn_s_setprio(1);
  #pragma unroll
  for (int m = 0; m < 6; ++m)
    #pragma unroll
    for (int n = 0; n < 3; ++n)
      acc[m][n] = __builtin_amdgcn_mfma_f32_16x16x32_bf16(a[m], b[n], acc[m][n], 0, 0, 0);
  __builtin_amdgcn_s_setprio(0);
}

// ---- main fused kernel: 192^2 upper-tri tiles, counted-vmcnt 3-buffer pipeline
__global__ __launch_bounds__(512, 2) void gram_kernel(
    const ushort_t* __restrict__ Wb, const ushort_t* __restrict__ Gb,
    const float* __restrict__ sqbW, const float* __restrict__ sqbG,
    const float* __restrict__ scs, const double* __restrict__ ssp,
    double* __restrict__ u, double* __restrict__ v, double* __restrict__ P)
{
  __shared__ __align__(16) char lds[3][49152];   // 3 rotating buffers, 4 panels each
  __shared__ double pred[8], pred2[8];
  __shared__ float sS4;

  // T1: bijective XCD-chunked swizzle (nwg=253: q=31, r=5)
  const int orig = blockIdx.x;
  const int xcd = orig & 7;
  const int idx = orig >> 3;
  const int swz = (xcd < 5 ? xcd * 32 : 5 * 32 + (xcd - 5) * 31) + idx;

  // decode upper-triangular tile index: 0 <= bi <= bj < 22
  int t = swz;
  int bi = 0;
  while (t >= NT - bi) { t -= NT - bi; ++bi; }
  const int bj = bi + t;
  const bool offdiag = (bi != bj);

  const int tid = threadIdx.x;
  const int lane = tid & 63;
  const int wid = tid >> 6;
  const int wr = wid >> 2;      // 0..1  (96-row half)
  const int wc = wid & 3;       // 0..3  (48-col quarter)
  const int i0 = bi * TS;
  const int j0 = bj * TS;
  const int g = lane >> 4;
  const int lr = lane & 15;

  f32x4 accW[6][3], accG[6][3];
  #pragma unroll
  for (int m = 0; m < 6; ++m)
    #pragma unroll
    for (int n = 0; n < 3; ++n) { accW[m][n] = (f32x4)0.0f; accG[m][n] = (f32x4)0.0f; }

  const char* Wb8 = (const char*)Wb;
  const char* Gb8 = (const char*)Gb;

  // prologue: issue steps 0 and 1 (12 loads/thread outstanding)
  stage_step(Wb8, Gb8, i0, j0, 0, tid, lds[0]);
  stage_step(Wb8, Gb8, i0, j0, 1, tid, lds[1]);

  // steady state: wait only for the oldest step's 6 loads (T4 counted vmcnt),
  // one raw barrier per K-step, prefetch depth 2.
  #pragma unroll
  for (int st = 0; st < 15; ++st) {
    asm volatile("s_waitcnt vmcnt(6)" ::: "memory");
    __builtin_amdgcn_s_barrier();
    __builtin_amdgcn_sched_barrier(0);
    if (st < 14)
      stage_step(Wb8, Gb8, i0, j0, st + 2, tid, lds[(st + 2) % 3]);
    gram_pass(lds[st % 3], wr, wc, lr, g, accW);
    gram_pass(lds[st % 3] + 24576, wr, wc, lr, g, accG);
  }
  asm volatile("s_waitcnt vmcnt(0)" ::: "memory");
  __builtin_amdgcn_s_barrier();
  __builtin_amdgcn_sched_barrier(0);
  gram_pass(lds[0], wr, wc, lr, g, accW);        // step 15 (15%3==0)
  gram_pass(lds[0] + 24576, wr, wc, lr, g, accG);

  // ---- folded bwk: compute bandwidth scale redundantly per block ----
  {
    float cs = 0.f;
    #pragma unroll 8
    for (int p = 0; p < 32; ++p) cs += scs[p * 512 + tid];
    double p1 = (double)cs * (double)cs;
    double p2 = (tid < 256) ? ssp[tid] : 0.0;
    #pragma unroll
    for (int off = 32; off > 0; off >>= 1) {
      p1 += __shfl_xor(p1, off);
      p2 += __shfl_xor(p2, off);
    }
    if (lane == 0) { pred[wid] = p1; pred2[wid] = p2; }
    __syncthreads();
    if (tid == 0) {
      double s2 = 0.0, ss = 0.0;
      #pragma unroll
      for (int k = 0; k < 8; ++k) { s2 += pred[k]; ss += pred2[k]; }
      double sum_d2 = 2.0 * 8192.0 * ss - 2.0 * s2;
      double bw = sum_d2 / (8192.0 * 8191.0) / 4.0;
      sS4 = (float)(1.4426950408889634 / (bw * 16.0));
    }
    __syncthreads();
  }
  const float s4 = sS4;

  // ---- epilogue: kernel values + reductions ----
  float rjW[3], rjG[3], mjf[3];
  #pragma unroll
  for (int n = 0; n < 3; ++n) {
    const int j = j0 + wc * 48 + n * 16 + lr;
    rjW[n] = sqbW[j]; rjG[n] = sqbG[j];
    mjf[n] = (j < NROW) ? 1.f : 0.f;
  }

  float csW[3] = {0.f, 0.f, 0.f}, csG[3] = {0.f, 0.f, 0.f};
  double p_loc = 0.0;

  #pragma unroll
  for (int m = 0; m < 6; ++m) {
    const int ib = i0 + wr * 96 + m * 16 + g * 4;
    float riW[4], riG[4], mif[4];
    #pragma unroll
    for (int e = 0; e < 4; ++e) {
      riW[e] = sqbW[ib + e]; riG[e] = sqbG[ib + e];
      mif[e] = (ib + e < NROW) ? 1.f : 0.f;
    }
    float rsW[4] = {0.f,0.f,0.f,0.f}, rsG[4] = {0.f,0.f,0.f,0.f};
    #pragma unroll
    for (int n = 0; n < 3; ++n) {
      #pragma unroll
      for (int e = 0; e < 4; ++e) {
        const float mk = mif[e] * mjf[n];
        float d2w = fmaxf(riW[e] + rjW[n] - 2.f * accW[m][n][e], 0.f);
        float yw = exp2f(-d2w * s4);
        float yw2 = yw * yw, yw4 = yw2 * yw2, yw8 = yw4 * yw4, yw16 = yw8 * yw8;
        float kw = (yw + yw2 + yw4 + yw8 + yw16) * mk;
        float d2g = fmaxf(riG[e] + rjG[n] - 2.f * accG[m][n][e], 0.f);
        float yg = exp2f(-d2g * s4);
        float yg2 = yg * yg, yg4 = yg2 * yg2, yg8 = yg4 * yg4, yg16 = yg8 * yg8;
        float kg = (yg + yg2 + yg4 + yg8 + yg16) * mk;
        p_loc += (double)(kw * kg);
        rsW[e] += kw; rsG[e] += kg;
        csW[n] += kw; csG[n] += kg;
      }
    }
    // row sums: butterfly across the 16 column-lanes, one f64 atomic per row
    #pragma unroll
    for (int e = 0; e < 4; ++e) {
      float x = rsW[e], y = rsG[e];
      x += __shfl_xor(x, 1); x += __shfl_xor(x, 2); x += __shfl_xor(x, 4); x += __shfl_xor(x, 8);
      y += __shfl_xor(y, 1); y += __shfl_xor(y, 2); y += __shfl_xor(y, 4); y += __shfl_xor(y, 8);
      if (lr == 0) {
        atomAddF64(&u[ib + e], (double)x);
        atomAddF64(&v[ib + e], (double)y);
      }
    }
  }

  // off-diagonal: column sums feed the transposed half (K symmetric)
  if (offdiag) {
    #pragma unroll
    for (int n = 0; n < 3; ++n) {
      float x = csW[n], y = csG[n];
      x += __shfl_xor(x, 16); x += __shfl_xor(x, 32);
      y += __shfl_xor(y, 16); y += __shfl_xor(y, 32);
      if (g == 0) {
        const int j = j0 + wc * 48 + n * 16 + lr;
        atomAddF64(&u[j], (double)x);
        atomAddF64(&v[j], (double)y);
      }
    }
  }

  // P: wave butterfly then one atomic per block (off-diag counts twice)
  #pragma unroll
  for (int off = 32; off > 0; off >>= 1) p_loc += __shfl_xor(p_loc, off);
  __syncthreads();   // pred[] reuse barrier
  if (lane == 0) pred[wid] = p_loc;
  __syncthreads();
  if (tid == 0) {
    double ps = 0.0;
    #pragma unroll
    for (int k = 0; k < 8; ++k) ps += pred[k];
    atomAddF64(P, offdiag ? 2.0 * ps : ps);
  }
}

// ---- finalize: loss = -(P - (2/n) u.v + Su*Sv/n^2) / (n-1)^2
__global__ __launch_bounds__(256) void finalize(
    const double* __restrict__ u, const double* __restrict__ v,
    const double* __restrict__ P, float* __restrict__ out)
{
  __shared__ double r0[256], r1[256], r2[256];
  const int t = threadIdx.x;
  double uv = 0.0, su = 0.0, sv = 0.0;
  for (int i = t; i < NROW; i += 256) { double a = u[i], b = v[i]; uv += a * b; su += a; sv += b; }
  r0[t] = uv; r1[t] = su; r2[t] = sv; __syncthreads();
  for (int k = 128; k > 0; k >>= 1) {
    if (t < k) { r0[t] += r0[t + k]; r1[t] += r1[t + k]; r2[t] += r2[t + k]; }
    __syncthreads();
  }
  if (t == 0) {
    const double n = 4096.0;
    double hsic = P[0] - (2.0 / n) * r0[0] + (r1[0] * r2[0]) / (n * n);
    out[0] = (float)(-hsic / ((n - 1.0) * (n - 1.0)));
  }
}

extern "C" void kernel_launch(void* const* d_in, const int* in_sizes, int n_in,
                              void* d_out, int out_size, void* d_ws, size_t ws_size,
                              hipStream_t stream) {
  const float* W = (const float*)d_in[0];
  const float* G = (const float*)d_in[1];
  char* ws = (char*)d_ws;
  ushort_t* Wb = (ushort_t*)(ws + WB_OFF);
  ushort_t* Gb = (ushort_t*)(ws + GB_OFF);
  float* sqbW = (float*)(ws + SQBW_OFF);
  float* sqbG = (float*)(ws + SQBG_OFF);
  double* u = (double*)(ws + U_OFF);
  double* v = (double*)(ws + V_OFF);
  float* scs = (float*)(ws + SCS_OFF);
  double* ssp = (double*)(ws + SSP_OFF);
  double* P = (double*)(ws + SC_OFF);

  hipMemsetAsync(ws + U_OFF, 0, ZERO_END - U_OFF, stream);

  prep_rows<<<2112, 256, 0, stream>>>(W, G, Wb, Gb, sqbW, sqbG, ssp, scs);
  gram_kernel<<<253, 512, 0, stream>>>(Wb, Gb, sqbW, sqbG, scs, ssp, u, v, P);
  finalize<<<1, 256, 0, stream>>>(u, v, P, (float*)d_out);
}

// Round 6
// 80.906 us; speedup vs baseline: 1.2785x; 1.0353x over previous
//
#include <hip/hip_runtime.h>
#include <stdint.h>

typedef __attribute__((ext_vector_type(4))) float f32x4;
typedef __attribute__((ext_vector_type(2))) unsigned int u32x2;

#define NROW 4096
#define DDIM 512
#define NT   22            // tiles per dim
#define TS   192

// ---------------- ws layout (bytes) ----------------
#define WB_OFF   0u          // fp8[4224*512] = 2162688
#define GB_OFF   2162688u    // fp8[4224*512]
#define SQBW_OFF 4325376u    // float[4224]
#define SQBG_OFF 4342272u    // float[4224]
#define U_OFF    4359168u    // double[4224] (zeroed)
#define V_OFF    4392960u    // double[4224] (zeroed)
#define SCS_OFF  4426752u    // float[32][512] (zeroed)
#define SSP_OFF  4492288u    // double[256] (zeroed)
#define SC_OFF   4494336u    // P double (zeroed)
#define ZERO_END 4494344u

__device__ __forceinline__ void atomAddF64(double* p, double v) {
  __hip_atomic_fetch_add(p, v, __ATOMIC_RELAXED, __HIP_MEMORY_SCOPE_AGENT);
}
__device__ __forceinline__ void atomAddF32(float* p, float v) {
  __hip_atomic_fetch_add(p, v, __ATOMIC_RELAXED, __HIP_MEMORY_SCOPE_AGENT);
}

// ---- fp8 e4m3fn helpers (decode is format-exact; encode prefers HW cvt) ----
__device__ __forceinline__ float fp8dec(unsigned b) {
  unsigned e = (b >> 3) & 15u, m = b & 7u;
  float v = ldexpf((float)(e ? (m | 8u) : m), (int)e - 10 + (e == 0));
  return (b & 0x80u) ? -v : v;
}

__device__ __forceinline__ unsigned f2fp8_manual(float f) {
  unsigned u = __float_as_uint(f);
  unsigned s = (u >> 24) & 0x80u;
  float a = __uint_as_float(u & 0x7FFFFFFFu);
  if (a >= 448.f) return s | 0x7Eu;           // saturate to 448
  if (a >= 0.015625f) {                       // normal (>= 2^-6)
    unsigned au = __float_as_uint(a);
    au += 0x7FFFFu + ((au >> 20) & 1u);       // RNE into 3-bit mantissa
    unsigned e = (au >> 23) - 120u;           // bias 127 -> 7
    unsigned m = (au >> 20) & 7u;
    if (e >= 16u) return s | 0x7Eu;
    return s | (e << 3) | m;
  }
  int q = (int)rintf(a * 512.f);              // denormal: multiples of 2^-9
  return s | (unsigned)q;                     // q==8 -> min normal 2^-6
}

#if __has_builtin(__builtin_amdgcn_cvt_pk_fp8_f32)
__device__ __forceinline__ unsigned pack4_fp8(float x0, float x1, float x2, float x3) {
  unsigned p = __builtin_amdgcn_cvt_pk_fp8_f32(x0, x1, 0, false);
  p = __builtin_amdgcn_cvt_pk_fp8_f32(x2, x3, p, true);
  return p;
}
#else
__device__ __forceinline__ unsigned pack4_fp8(float x0, float x1, float x2, float x3) {
  return f2fp8_manual(x0) | (f2fp8_manual(x1) << 8) |
         (f2fp8_manual(x2) << 16) | (f2fp8_manual(x3) << 24);
}
#endif

__device__ __forceinline__ void gload16(const void* g, void* l) {
  __builtin_amdgcn_global_load_lds(
      (const __attribute__((address_space(1))) unsigned int*)g,
      (__attribute__((address_space(3))) unsigned int*)l, 16, 0, 0);
}

// ---- prep: fp32->fp8 e4m3 (+zero pad rows), fp8-consistent row sumsq, fused column sums
__global__ __launch_bounds__(256) void prep_rows(
    const float* __restrict__ W, const float* __restrict__ G,
    unsigned char* __restrict__ Wb, unsigned char* __restrict__ Gb,
    float* __restrict__ sqbW, float* __restrict__ sqbG,
    double* __restrict__ ssp, float* __restrict__ scs)
{
  __shared__ float cols[4][512];
  const int bid = blockIdx.x;
  const int w = threadIdx.x >> 6;
  const int l = threadIdx.x & 63;

  if (bid >= 2048) {                       // pad-row zeroing blocks
    const int pr = (bid - 2048) * 4 + w;   // 0..255
    const bool isG = pr >= 128;
    const int row = NROW + (pr & 127);     // 4096..4223
    unsigned char* dst = (isG ? Gb : Wb) + (size_t)row * DDIM;
    *(u32x2*)(dst + l * 8) = (u32x2){0u, 0u};
    if (l == 0) (isG ? sqbG : sqbW)[row] = 0.f;
    return;
  }

  const int row = bid * 4 + w;             // 0..8191
  const float* src; unsigned char* dst; float* sqb; int r;
  if (row < NROW) { src = W + (size_t)row * DDIM; dst = Wb + (size_t)row * DDIM; sqb = sqbW; r = row; }
  else            { src = G + (size_t)(row - NROW) * DDIM; dst = Gb + (size_t)(row - NROW) * DDIM; sqb = sqbG; r = row - NROW; }
  const f32x4 a = *(const f32x4*)(src + l * 8);
  const f32x4 b = *(const f32x4*)(src + l * 8 + 4);

  const unsigned p0 = pack4_fp8(a[0], a[1], a[2], a[3]);
  const unsigned p1 = pack4_fp8(b[0], b[1], b[2], b[3]);
  *(u32x2*)(dst + l * 8) = (u32x2){p0, p1};

  float s32 = 0.f, sb = 0.f;
  #pragma unroll
  for (int j = 0; j < 4; ++j) { s32 += a[j] * a[j]; s32 += b[j] * b[j]; }
  #pragma unroll
  for (int j = 0; j < 4; ++j) {
    float xa = fp8dec((p0 >> (8 * j)) & 0xFFu);
    float xb = fp8dec((p1 >> (8 * j)) & 0xFFu);
    sb += xa * xa + xb * xb;
  }

  // fused column sums (fp32 source values)
  *(f32x4*)&cols[w][l * 8] = a;
  *(f32x4*)&cols[w][l * 8 + 4] = b;
  __syncthreads();
  for (int c = threadIdx.x; c < 512; c += 256)
    atomAddF32(&scs[(bid & 31) * 512 + c],
               cols[0][c] + cols[1][c] + cols[2][c] + cols[3][c]);

  #pragma unroll
  for (int off = 32; off > 0; off >>= 1) { s32 += __shfl_down(s32, off); sb += __shfl_down(sb, off); }
  if (l == 0) { sqb[r] = sb; atomAddF64(&ssp[bid & 255], (double)s32); }
}

// ---- stage one BK=64 K-step: 4 fp8 panels AW|BW|AG|BG (192x64 B = 12288 B each)
// linear LDS dest; global source 16B-slot pre-swizzled: c = s ^ ((row>>1)&3)  (rule #21)
__device__ __forceinline__ void stage_step(
    const unsigned char* __restrict__ Wb, const unsigned char* __restrict__ Gb,
    int i0, int j0, int st, int tid, unsigned char* buf)
{
  const int kb = st * 64;
  #pragma unroll
  for (int q = 0; q < 6; ++q) {
    const int slot = q * 512 + tid;   // 0..3071, 16B each; panels of 768 slots
    int p;
    if (q == 0) p = 0;
    else if (q == 1) p = (slot < 768) ? 0 : 1;
    else if (q == 2) p = 1;
    else if (q == 3) p = 2;
    else if (q == 4) p = (slot < 2304) ? 2 : 3;
    else p = 3;
    const unsigned char* mat = (p < 2) ? Wb : Gb;
    const int rb = (p & 1) ? j0 : i0;
    const int r = slot - p * 768;
    const int row = r >> 2;
    const int c = (r & 3) ^ ((row >> 1) & 3);
    gload16(mat + (size_t)(rb + row) * 512 + kb + c * 16, buf + slot * 16);
  }
}

// ---- one K=64 step (2 x K=32 MFMA) for one gram from staged fp8 panels
__device__ __forceinline__ void gram_pass(
    const unsigned char* __restrict__ A, const unsigned char* __restrict__ B,
    int wr, int wc, int lr, int g, f32x4 acc[6][3])
{
  #pragma unroll
  for (int kk = 0; kk < 2; ++kk) {
    long long a[6], b[3];
    #pragma unroll
    for (int m = 0; m < 6; ++m) {
      const int row = wr * 96 + m * 16 + lr;
      const int off = row * 64 + (((kk * 2 + (g >> 1)) ^ ((row >> 1) & 3)) << 4) + ((g & 1) << 3);
      a[m] = *(const long long*)(A + off);
    }
    #pragma unroll
    for (int n = 0; n < 3; ++n) {
      const int row = wc * 48 + n * 16 + lr;
      const int off = row * 64 + (((kk * 2 + (g >> 1)) ^ ((row >> 1) & 3)) << 4) + ((g & 1) << 3);
      b[n] = *(const long long*)(B + off);
    }
    __builtin_amdgcn_s_setprio(1);
    #pragma unroll
    for (int m = 0; m < 6; ++m)
      #pragma unroll
      for (int n = 0; n < 3; ++n)
        acc[m][n] = __builtin_amdgcn_mfma_f32_16x16x32_fp8_fp8(a[m], b[n], acc[m][n], 0, 0, 0);
    __builtin_amdgcn_s_setprio(0);
  }
}

// ---- main fused kernel: 192^2 upper-tri tiles, fp8 grams, reductions, folded bwk
__global__ __launch_bounds__(512, 2) void gram_kernel(
    const unsigned char* __restrict__ Wb, const unsigned char* __restrict__ Gb,
    const float* __restrict__ sqbW, const float* __restrict__ sqbG,
    const float* __restrict__ scs, const double* __restrict__ ssp,
    double* __restrict__ u, double* __restrict__ v, double* __restrict__ P)
{
  __shared__ __align__(16) unsigned char lds[49152];   // AW|BW|AG|BG
  __shared__ double pred[8], pred2[8];
  __shared__ float sS4;

  // T1: bijective XCD-chunked swizzle (nwg=253: q=31, r=5)
  const int orig = blockIdx.x;
  const int xcd = orig & 7;
  const int idx = orig >> 3;
  const int swz = (xcd < 5 ? xcd * 32 : 5 * 32 + (xcd - 5) * 31) + idx;

  // decode upper-triangular tile index: 0 <= bi <= bj < 22
  int t = swz;
  int bi = 0;
  while (t >= NT - bi) { t -= NT - bi; ++bi; }
  const int bj = bi + t;
  const bool offdiag = (bi != bj);

  const int tid = threadIdx.x;
  const int lane = tid & 63;
  const int wid = tid >> 6;
  const int wr = wid >> 2;      // 0..1  (96-row half)
  const int wc = wid & 3;       // 0..3  (48-col quarter)
  const int i0 = bi * TS;
  const int j0 = bj * TS;
  const int g = lane >> 4;
  const int lr = lane & 15;

  f32x4 accW[6][3], accG[6][3];
  #pragma unroll
  for (int m = 0; m < 6; ++m)
    #pragma unroll
    for (int n = 0; n < 3; ++n) { accW[m][n] = (f32x4)0.0f; accG[m][n] = (f32x4)0.0f; }

  for (int st = 0; st < 8; ++st) {
    stage_step(Wb, Gb, i0, j0, st, tid, lds);
    __syncthreads();
    gram_pass(lds, lds + 12288, wr, wc, lr, g, accW);
    gram_pass(lds + 24576, lds + 36864, wr, wc, lr, g, accG);
    __syncthreads();
  }

  // ---- folded bwk: bandwidth scale computed redundantly per block ----
  {
    float cs = 0.f;
    #pragma unroll 8
    for (int p = 0; p < 32; ++p) cs += scs[p * 512 + tid];
    double p1 = (double)cs * (double)cs;
    double p2 = (tid < 256) ? ssp[tid] : 0.0;
    #pragma unroll
    for (int off = 32; off > 0; off >>= 1) {
      p1 += __shfl_xor(p1, off);
      p2 += __shfl_xor(p2, off);
    }
    if (lane == 0) { pred[wid] = p1; pred2[wid] = p2; }
    __syncthreads();
    if (tid == 0) {
      double s2 = 0.0, ss = 0.0;
      #pragma unroll
      for (int k = 0; k < 8; ++k) { s2 += pred[k]; ss += pred2[k]; }
      double sum_d2 = 2.0 * 8192.0 * ss - 2.0 * s2;
      double bw = sum_d2 / (8192.0 * 8191.0) / 4.0;
      sS4 = (float)(1.4426950408889634 / (bw * 16.0));
    }
    __syncthreads();
  }
  const float s4 = sS4;

  // ---- epilogue: kernel values + reductions ----
  float rjW[3], rjG[3], mjf[3];
  #pragma unroll
  for (int n = 0; n < 3; ++n) {
    const int j = j0 + wc * 48 + n * 16 + lr;
    rjW[n] = sqbW[j]; rjG[n] = sqbG[j];
    mjf[n] = (j < NROW) ? 1.f : 0.f;
  }

  float csW[3] = {0.f, 0.f, 0.f}, csG[3] = {0.f, 0.f, 0.f};
  double p_loc = 0.0;

  #pragma unroll
  for (int m = 0; m < 6; ++m) {
    const int ib = i0 + wr * 96 + m * 16 + g * 4;
    float riW[4], riG[4], mif[4];
    #pragma unroll
    for (int e = 0; e < 4; ++e) {
      riW[e] = sqbW[ib + e]; riG[e] = sqbG[ib + e];
      mif[e] = (ib + e < NROW) ? 1.f : 0.f;
    }
    float rsW[4] = {0.f,0.f,0.f,0.f}, rsG[4] = {0.f,0.f,0.f,0.f};
    #pragma unroll
    for (int n = 0; n < 3; ++n) {
      #pragma unroll
      for (int e = 0; e < 4; ++e) {
        const float mk = mif[e] * mjf[n];
        float d2w = fmaxf(riW[e] + rjW[n] - 2.f * accW[m][n][e], 0.f);
        float yw = exp2f(-d2w * s4);
        float yw2 = yw * yw, yw4 = yw2 * yw2, yw8 = yw4 * yw4, yw16 = yw8 * yw8;
        float kw = (yw + yw2 + yw4 + yw8 + yw16) * mk;
        float d2g = fmaxf(riG[e] + rjG[n] - 2.f * accG[m][n][e], 0.f);
        float yg = exp2f(-d2g * s4);
        float yg2 = yg * yg, yg4 = yg2 * yg2, yg8 = yg4 * yg4, yg16 = yg8 * yg8;
        float kg = (yg + yg2 + yg4 + yg8 + yg16) * mk;
        p_loc += (double)(kw * kg);
        rsW[e] += kw; rsG[e] += kg;
        csW[n] += kw; csG[n] += kg;
      }
    }
    // row sums: butterfly across the 16 column-lanes, one f64 atomic per row
    #pragma unroll
    for (int e = 0; e < 4; ++e) {
      float x = rsW[e], y = rsG[e];
      x += __shfl_xor(x, 1); x += __shfl_xor(x, 2); x += __shfl_xor(x, 4); x += __shfl_xor(x, 8);
      y += __shfl_xor(y, 1); y += __shfl_xor(y, 2); y += __shfl_xor(y, 4); y += __shfl_xor(y, 8);
      if (lr == 0) {
        atomAddF64(&u[ib + e], (double)x);
        atomAddF64(&v[ib + e], (double)y);
      }
    }
  }

  // off-diagonal: column sums feed the transposed half (K symmetric)
  if (offdiag) {
    #pragma unroll
    for (int n = 0; n < 3; ++n) {
      float x = csW[n], y = csG[n];
      x += __shfl_xor(x, 16); x += __shfl_xor(x, 32);
      y += __shfl_xor(y, 16); y += __shfl_xor(y, 32);
      if (g == 0) {
        const int j = j0 + wc * 48 + n * 16 + lr;
        atomAddF64(&u[j], (double)x);
        atomAddF64(&v[j], (double)y);
      }
    }
  }

  // P: wave butterfly then one atomic per block (off-diag counts twice)
  #pragma unroll
  for (int off = 32; off > 0; off >>= 1) p_loc += __shfl_xor(p_loc, off);
  __syncthreads();   // pred[] reuse barrier
  if (lane == 0) pred[wid] = p_loc;
  __syncthreads();
  if (tid == 0) {
    double ps = 0.0;
    #pragma unroll
    for (int k = 0; k < 8; ++k) ps += pred[k];
    atomAddF64(P, offdiag ? 2.0 * ps : ps);
  }
}

// ---- finalize: loss = -(P - (2/n) u.v + Su*Sv/n^2) / (n-1)^2
__global__ __launch_bounds__(256) void finalize(
    const double* __restrict__ u, const double* __restrict__ v,
    const double* __restrict__ P, float* __restrict__ out)
{
  __shared__ double r0[256], r1[256], r2[256];
  const int t = threadIdx.x;
  double uv = 0.0, su = 0.0, sv = 0.0;
  for (int i = t; i < NROW; i += 256) { double a = u[i], b = v[i]; uv += a * b; su += a; sv += b; }
  r0[t] = uv; r1[t] = su; r2[t] = sv; __syncthreads();
  for (int k = 128; k > 0; k >>= 1) {
    if (t < k) { r0[t] += r0[t + k]; r1[t] += r1[t + k]; r2[t] += r2[t + k]; }
    __syncthreads();
  }
  if (t == 0) {
    const double n = 4096.0;
    double hsic = P[0] - (2.0 / n) * r0[0] + (r1[0] * r2[0]) / (n * n);
    out[0] = (float)(-hsic / ((n - 1.0) * (n - 1.0)));
  }
}

extern "C" void kernel_launch(void* const* d_in, const int* in_sizes, int n_in,
                              void* d_out, int out_size, void* d_ws, size_t ws_size,
                              hipStream_t stream) {
  const float* W = (const float*)d_in[0];
  const float* G = (const float*)d_in[1];
  char* ws = (char*)d_ws;
  unsigned char* Wb = (unsigned char*)(ws + WB_OFF);
  unsigned char* Gb = (unsigned char*)(ws + GB_OFF);
  float* sqbW = (float*)(ws + SQBW_OFF);
  float* sqbG = (float*)(ws + SQBG_OFF);
  double* u = (double*)(ws + U_OFF);
  double* v = (double*)(ws + V_OFF);
  float* scs = (float*)(ws + SCS_OFF);
  double* ssp = (double*)(ws + SSP_OFF);
  double* P = (double*)(ws + SC_OFF);

  hipMemsetAsync(ws + U_OFF, 0, ZERO_END - U_OFF, stream);

  prep_rows<<<2112, 256, 0, stream>>>(W, G, Wb, Gb, sqbW, sqbG, ssp, scs);
  gram_kernel<<<253, 512, 0, stream>>>(Wb, Gb, sqbW, sqbG, scs, ssp, u, v, P);
  finalize<<<1, 256, 0, stream>>>(u, v, P, (float*)d_out);
}

// Round 8
// 64.917 us; speedup vs baseline: 1.5933x; 1.2463x over previous
//
#include <hip/hip_runtime.h>
#include <stdint.h>

typedef __attribute__((ext_vector_type(4))) float f32x4;
typedef __attribute__((ext_vector_type(2))) unsigned int u32x2;

#define NROW 4096
#define DDIM 512
#define NT   22            // tiles per dim
#define TS   192

// ---------------- ws layout (bytes) ----------------
#define WB_OFF   0u          // fp8[4224*512] = 2162688
#define GB_OFF   2162688u    // fp8[4224*512]
#define SQBW_OFF 4325376u    // float[4224]
#define SQBG_OFF 4342272u    // float[4224]
#define SCS_OFF  4359168u    // float[32][512] (zeroed)
#define SSP_OFF  4424704u    // double[256]    (zeroed)
#define PU_OFF   4426752u    // float[22][22][192] = 371712 (fully written)
#define PV_OFF   4798464u    // float[22][22][192]
#define PSL_OFF  5170176u    // double[253]    (fully written)
#define FSL_OFF  5172200u    // double[33][3]  (fully written)
#define ZERO_BEG SCS_OFF
#define ZERO_END (SSP_OFF + 2048u)

__device__ __forceinline__ void atomAddF64(double* p, double v) {
  __hip_atomic_fetch_add(p, v, __ATOMIC_RELAXED, __HIP_MEMORY_SCOPE_AGENT);
}
__device__ __forceinline__ void atomAddF32(float* p, float v) {
  __hip_atomic_fetch_add(p, v, __ATOMIC_RELAXED, __HIP_MEMORY_SCOPE_AGENT);
}

// ---- fp8 e4m3fn helpers (decode is format-exact; encode prefers HW cvt) ----
__device__ __forceinline__ float fp8dec(unsigned b) {
  unsigned e = (b >> 3) & 15u, m = b & 7u;
  float v = ldexpf((float)(e ? (m | 8u) : m), (int)e - 10 + (e == 0));
  return (b & 0x80u) ? -v : v;
}

__device__ __forceinline__ unsigned f2fp8_manual(float f) {
  unsigned u = __float_as_uint(f);
  unsigned s = (u >> 24) & 0x80u;
  float a = __uint_as_float(u & 0x7FFFFFFFu);
  if (a >= 448.f) return s | 0x7Eu;           // saturate to 448
  if (a >= 0.015625f) {                       // normal (>= 2^-6)
    unsigned au = __float_as_uint(a);
    au += 0x7FFFFu + ((au >> 20) & 1u);       // RNE into 3-bit mantissa
    unsigned e = (au >> 23) - 120u;           // bias 127 -> 7
    unsigned m = (au >> 20) & 7u;
    if (e >= 16u) return s | 0x7Eu;
    return s | (e << 3) | m;
  }
  int q = (int)rintf(a * 512.f);              // denormal: multiples of 2^-9
  return s | (unsigned)q;                     // q==8 -> min normal 2^-6
}

#if __has_builtin(__builtin_amdgcn_cvt_pk_fp8_f32)
__device__ __forceinline__ unsigned pack4_fp8(float x0, float x1, float x2, float x3) {
  unsigned p = __builtin_amdgcn_cvt_pk_fp8_f32(x0, x1, 0, false);
  p = __builtin_amdgcn_cvt_pk_fp8_f32(x2, x3, p, true);
  return p;
}
#else
__device__ __forceinline__ unsigned pack4_fp8(float x0, float x1, float x2, float x3) {
  return f2fp8_manual(x0) | (f2fp8_manual(x1) << 8) |
         (f2fp8_manual(x2) << 16) | (f2fp8_manual(x3) << 24);
}
#endif

__device__ __forceinline__ void gload16(const void* g, void* l) {
  __builtin_amdgcn_global_load_lds(
      (const __attribute__((address_space(1))) unsigned int*)g,
      (__attribute__((address_space(3))) unsigned int*)l, 16, 0, 0);
}

// ---- prep: fp32->fp8 e4m3 (+zero pad rows), fp8-consistent row sumsq, fused column sums
__global__ __launch_bounds__(256) void prep_rows(
    const float* __restrict__ W, const float* __restrict__ G,
    unsigned char* __restrict__ Wb, unsigned char* __restrict__ Gb,
    float* __restrict__ sqbW, float* __restrict__ sqbG,
    double* __restrict__ ssp, float* __restrict__ scs)
{
  __shared__ float cols[4][512];
  const int bid = blockIdx.x;
  const int w = threadIdx.x >> 6;
  const int l = threadIdx.x & 63;

  if (bid >= 2048) {                       // pad-row zeroing blocks
    const int pr = (bid - 2048) * 4 + w;   // 0..255
    const bool isG = pr >= 128;
    const int row = NROW + (pr & 127);     // 4096..4223
    unsigned char* dst = (isG ? Gb : Wb) + (size_t)row * DDIM;
    *(u32x2*)(dst + l * 8) = (u32x2){0u, 0u};
    if (l == 0) (isG ? sqbG : sqbW)[row] = 0.f;
    return;
  }

  const int row = bid * 4 + w;             // 0..8191
  const float* src; unsigned char* dst; float* sqb; int r;
  if (row < NROW) { src = W + (size_t)row * DDIM; dst = Wb + (size_t)row * DDIM; sqb = sqbW; r = row; }
  else            { src = G + (size_t)(row - NROW) * DDIM; dst = Gb + (size_t)(row - NROW) * DDIM; sqb = sqbG; r = row - NROW; }
  const f32x4 a = *(const f32x4*)(src + l * 8);
  const f32x4 b = *(const f32x4*)(src + l * 8 + 4);

  const unsigned p0 = pack4_fp8(a[0], a[1], a[2], a[3]);
  const unsigned p1 = pack4_fp8(b[0], b[1], b[2], b[3]);
  *(u32x2*)(dst + l * 8) = (u32x2){p0, p1};

  float s32 = 0.f, sb = 0.f;
  #pragma unroll
  for (int j = 0; j < 4; ++j) { s32 += a[j] * a[j]; s32 += b[j] * b[j]; }
  #pragma unroll
  for (int j = 0; j < 4; ++j) {
    float xa = fp8dec((p0 >> (8 * j)) & 0xFFu);
    float xb = fp8dec((p1 >> (8 * j)) & 0xFFu);
    sb += xa * xa + xb * xb;
  }

  // fused column sums (fp32 source values); f32 atomics are L2-native (cheap)
  *(f32x4*)&cols[w][l * 8] = a;
  *(f32x4*)&cols[w][l * 8 + 4] = b;
  __syncthreads();
  for (int c = threadIdx.x; c < 512; c += 256)
    atomAddF32(&scs[(bid & 31) * 512 + c],
               cols[0][c] + cols[1][c] + cols[2][c] + cols[3][c]);

  #pragma unroll
  for (int off = 32; off > 0; off >>= 1) { s32 += __shfl_down(s32, off); sb += __shfl_down(sb, off); }
  if (l == 0) { sqb[r] = sb; atomAddF64(&ssp[bid & 255], (double)s32); }
}

// ---- stage one BK=64 K-step: 4 fp8 panels AW|BW|AG|BG (192x64 B = 12288 B each)
__device__ __forceinline__ void stage_step(
    const unsigned char* __restrict__ Wb, const unsigned char* __restrict__ Gb,
    int i0, int j0, int st, int tid, unsigned char* buf)
{
  const int kb = st * 64;
  #pragma unroll
  for (int q = 0; q < 6; ++q) {
    const int slot = q * 512 + tid;   // 0..3071, 16B each; panels of 768 slots
    int p;
    if (q == 0) p = 0;
    else if (q == 1) p = (slot < 768) ? 0 : 1;
    else if (q == 2) p = 1;
    else if (q == 3) p = 2;
    else if (q == 4) p = (slot < 2304) ? 2 : 3;
    else p = 3;
    const unsigned char* mat = (p < 2) ? Wb : Gb;
    const int rb = (p & 1) ? j0 : i0;
    const int r = slot - p * 768;
    const int row = r >> 2;
    const int c = (r & 3) ^ ((row >> 1) & 3);
    gload16(mat + (size_t)(rb + row) * 512 + kb + c * 16, buf + slot * 16);
  }
}

// ---- one K=64 step (2 x K=32 MFMA) for one gram from staged fp8 panels
__device__ __forceinline__ void gram_pass(
    const unsigned char* __restrict__ A, const unsigned char* __restrict__ B,
    int wr, int wc, int lr, int g, f32x4 acc[6][3])
{
  #pragma unroll
  for (int kk = 0; kk < 2; ++kk) {
    long long a[6], b[3];
    #pragma unroll
    for (int m = 0; m < 6; ++m) {
      const int row = wr * 96 + m * 16 + lr;
      const int off = row * 64 + (((kk * 2 + (g >> 1)) ^ ((row >> 1) & 3)) << 4) + ((g & 1) << 3);
      a[m] = *(const long long*)(A + off);
    }
    #pragma unroll
    for (int n = 0; n < 3; ++n) {
      const int row = wc * 48 + n * 16 + lr;
      const int off = row * 64 + (((kk * 2 + (g >> 1)) ^ ((row >> 1) & 3)) << 4) + ((g & 1) << 3);
      b[n] = *(const long long*)(B + off);
    }
    __builtin_amdgcn_s_setprio(1);
    #pragma unroll
    for (int m = 0; m < 6; ++m)
      #pragma unroll
      for (int n = 0; n < 3; ++n)
        acc[m][n] = __builtin_amdgcn_mfma_f32_16x16x32_fp8_fp8(a[m], b[n], acc[m][n], 0, 0, 0);
    __builtin_amdgcn_s_setprio(0);
  }
}

// ---- main fused kernel: fp8 grams; NO global atomics — per-tile partial stores
__global__ __launch_bounds__(512, 2) void gram_kernel(
    const unsigned char* __restrict__ Wb, const unsigned char* __restrict__ Gb,
    const float* __restrict__ sqbW, const float* __restrict__ sqbG,
    const float* __restrict__ scs, const double* __restrict__ ssp,
    float* __restrict__ PU, float* __restrict__ PV, double* __restrict__ PSL)
{
  __shared__ __align__(16) unsigned char lds[49152];   // AW|BW|AG|BG ; reused as float L[]
  __shared__ double pred[8], pred2[8];
  __shared__ float sS4;
  float* L = (float*)lds;   // [0:192)=rowW [192:384)=rowG [384:576)=colW [576:768)=colG

  // T1: bijective XCD-chunked swizzle (nwg=253: q=31, r=5)
  const int orig = blockIdx.x;
  const int xcd = orig & 7;
  const int idx = orig >> 3;
  const int swz = (xcd < 5 ? xcd * 32 : 5 * 32 + (xcd - 5) * 31) + idx;

  // decode upper-triangular tile index: 0 <= bi <= bj < 22
  int t = swz;
  int bi = 0;
  while (t >= NT - bi) { t -= NT - bi; ++bi; }
  const int bj = bi + t;
  const bool offdiag = (bi != bj);

  const int tid = threadIdx.x;
  const int lane = tid & 63;
  const int wid = tid >> 6;
  const int wr = wid >> 2;      // 0..1  (96-row half)
  const int wc = wid & 3;       // 0..3  (48-col quarter)
  const int i0 = bi * TS;
  const int j0 = bj * TS;
  const int g = lane >> 4;
  const int lr = lane & 15;

  f32x4 accW[6][3], accG[6][3];
  #pragma unroll
  for (int m = 0; m < 6; ++m)
    #pragma unroll
    for (int n = 0; n < 3; ++n) { accW[m][n] = (f32x4)0.0f; accG[m][n] = (f32x4)0.0f; }

  for (int st = 0; st < 8; ++st) {
    stage_step(Wb, Gb, i0, j0, st, tid, lds);
    __syncthreads();
    gram_pass(lds, lds + 12288, wr, wc, lr, g, accW);
    gram_pass(lds + 24576, lds + 36864, wr, wc, lr, g, accG);
    __syncthreads();
  }

  // ---- folded bwk: bandwidth scale computed redundantly per block ----
  {
    float cs = 0.f;
    #pragma unroll 8
    for (int p = 0; p < 32; ++p) cs += scs[p * 512 + tid];
    double p1 = (double)cs * (double)cs;
    double p2 = (tid < 256) ? ssp[tid] : 0.0;
    #pragma unroll
    for (int off = 32; off > 0; off >>= 1) {
      p1 += __shfl_xor(p1, off);
      p2 += __shfl_xor(p2, off);
    }
    if (lane == 0) { pred[wid] = p1; pred2[wid] = p2; }
    __syncthreads();
    if (tid == 0) {
      double s2 = 0.0, ss = 0.0;
      #pragma unroll
      for (int k = 0; k < 8; ++k) { s2 += pred[k]; ss += pred2[k]; }
      double sum_d2 = 2.0 * 8192.0 * ss - 2.0 * s2;
      double bw = sum_d2 / (8192.0 * 8191.0) / 4.0;
      sS4 = (float)(1.4426950408889634 / (bw * 16.0));
    }
    __syncthreads();
  }
  const float s4 = sS4;

  // zero ALL 768 floats of the LDS reduction arrays (512 threads -> 2 passes;
  // R7 bug: `if (tid<768) L[tid]=0` left L[512..767] holding stale panel bytes)
  L[tid] = 0.f;
  if (tid < 256) L[512 + tid] = 0.f;

  // ---- epilogue: kernel values (registers only) ----
  float rjW[3], rjG[3], mjf[3];
  #pragma unroll
  for (int n = 0; n < 3; ++n) {
    const int j = j0 + wc * 48 + n * 16 + lr;
    rjW[n] = sqbW[j]; rjG[n] = sqbG[j];
    mjf[n] = (j < NROW) ? 1.f : 0.f;
  }

  float csW[3] = {0.f, 0.f, 0.f}, csG[3] = {0.f, 0.f, 0.f};
  float rsW[6][4], rsG[6][4];
  double p_loc = 0.0;

  #pragma unroll
  for (int m = 0; m < 6; ++m) {
    const int ib = i0 + wr * 96 + m * 16 + g * 4;
    float riW[4], riG[4], mif[4];
    #pragma unroll
    for (int e = 0; e < 4; ++e) {
      riW[e] = sqbW[ib + e]; riG[e] = sqbG[ib + e];
      mif[e] = (ib + e < NROW) ? 1.f : 0.f;
    }
    #pragma unroll
    for (int e = 0; e < 4; ++e) { rsW[m][e] = 0.f; rsG[m][e] = 0.f; }
    #pragma unroll
    for (int n = 0; n < 3; ++n) {
      #pragma unroll
      for (int e = 0; e < 4; ++e) {
        const float mk = mif[e] * mjf[n];
        float d2w = fmaxf(riW[e] + rjW[n] - 2.f * accW[m][n][e], 0.f);
        float yw = exp2f(-d2w * s4);
        float yw2 = yw * yw, yw4 = yw2 * yw2, yw8 = yw4 * yw4, yw16 = yw8 * yw8;
        float kw = (yw + yw2 + yw4 + yw8 + yw16) * mk;
        float d2g = fmaxf(riG[e] + rjG[n] - 2.f * accG[m][n][e], 0.f);
        float yg = exp2f(-d2g * s4);
        float yg2 = yg * yg, yg4 = yg2 * yg2, yg8 = yg4 * yg4, yg16 = yg8 * yg8;
        float kg = (yg + yg2 + yg4 + yg8 + yg16) * mk;
        p_loc += (double)(kw * kg);
        rsW[m][e] += kw; rsG[m][e] += kg;
        csW[n] += kw; csG[n] += kg;
      }
    }
  }

  __syncthreads();   // L zeroing visible to all

  // row sums -> LDS (butterfly over the 16 column-lanes, then 4-way LDS atomic)
  #pragma unroll
  for (int m = 0; m < 6; ++m)
    #pragma unroll
    for (int e = 0; e < 4; ++e) {
      float x = rsW[m][e], y = rsG[m][e];
      x += __shfl_xor(x, 1); x += __shfl_xor(x, 2); x += __shfl_xor(x, 4); x += __shfl_xor(x, 8);
      y += __shfl_xor(y, 1); y += __shfl_xor(y, 2); y += __shfl_xor(y, 4); y += __shfl_xor(y, 8);
      if (lr == 0) {
        const int rloc = wr * 96 + m * 16 + g * 4 + e;   // 0..191
        atomicAdd(&L[rloc], x);
        atomicAdd(&L[192 + rloc], y);
      }
    }

  // col sums -> LDS (butterfly over g-groups, then 2-way LDS atomic)
  if (offdiag) {
    #pragma unroll
    for (int n = 0; n < 3; ++n) {
      float x = csW[n], y = csG[n];
      x += __shfl_xor(x, 16); x += __shfl_xor(x, 32);
      y += __shfl_xor(y, 16); y += __shfl_xor(y, 32);
      if (g == 0) {
        const int cloc = wc * 48 + n * 16 + lr;          // 0..191
        atomicAdd(&L[384 + cloc], x);
        atomicAdd(&L[576 + cloc], y);
      }
    }
  }

  __syncthreads();

  // plain coalesced partial stores (no global atomics):
  // slot (b,k): row-part of tile (bi,bj) -> (bi,bj); col-part -> (bj,bi). Full coverage.
  if (tid < 192) {
    PU[(bi * NT + bj) * 192 + tid] = L[tid];
    PV[(bi * NT + bj) * 192 + tid] = L[192 + tid];
    if (offdiag) {
      PU[(bj * NT + bi) * 192 + tid] = L[384 + tid];
      PV[(bj * NT + bi) * 192 + tid] = L[576 + tid];
    }
  }

  // P: wave butterfly, block sum, ONE plain f64 store per tile
  #pragma unroll
  for (int off = 32; off > 0; off >>= 1) p_loc += __shfl_xor(p_loc, off);
  if (lane == 0) pred[wid] = p_loc;
  __syncthreads();
  if (tid == 0) {
    double ps = 0.0;
    #pragma unroll
    for (int k = 0; k < 8; ++k) ps += pred[k];
    PSL[swz] = offdiag ? 2.0 * ps : ps;
  }
}

// ---- finalize1: u[i],v[i] from partials; band-block partial (uv, su, sv)
__global__ __launch_bounds__(128) void finalize1(
    const float* __restrict__ PU, const float* __restrict__ PV,
    double* __restrict__ fsl)
{
  __shared__ double r0[128], r1[128], r2[128];
  const int t = threadIdx.x;
  const int i = blockIdx.x * 128 + t;      // 0..4223
  const int b = i / 192, ii = i % 192;
  double uu = 0.0, vv = 0.0;
  #pragma unroll
  for (int k = 0; k < NT; ++k) {
    uu += (double)PU[(b * NT + k) * 192 + ii];
    vv += (double)PV[(b * NT + k) * 192 + ii];
  }
  r0[t] = uu * vv; r1[t] = uu; r2[t] = vv;
  __syncthreads();
  for (int k = 64; k > 0; k >>= 1) {
    if (t < k) { r0[t] += r0[t + k]; r1[t] += r1[t + k]; r2[t] += r2[t + k]; }
    __syncthreads();
  }
  if (t == 0) {
    fsl[blockIdx.x * 3 + 0] = r0[0];
    fsl[blockIdx.x * 3 + 1] = r1[0];
    fsl[blockIdx.x * 3 + 2] = r2[0];
  }
}

// ---- finalize2: loss = -(P - (2/n) u.v + Su*Sv/n^2) / (n-1)^2
__global__ __launch_bounds__(256) void finalize2(
    const double* __restrict__ PSL, const double* __restrict__ fsl,
    float* __restrict__ out)
{
  __shared__ double r0[256], r1[256], r2[256], r3[256];
  const int t = threadIdx.x;
  double p = (t < 253) ? PSL[t] : 0.0;
  double uv = 0.0, su = 0.0, sv = 0.0;
  if (t < 33) { uv = fsl[t * 3 + 0]; su = fsl[t * 3 + 1]; sv = fsl[t * 3 + 2]; }
  r0[t] = uv; r1[t] = su; r2[t] = sv; r3[t] = p;
  __syncthreads();
  for (int k = 128; k > 0; k >>= 1) {
    if (t < k) { r0[t] += r0[t + k]; r1[t] += r1[t + k]; r2[t] += r2[t + k]; r3[t] += r3[t + k]; }
    __syncthreads();
  }
  if (t == 0) {
    const double n = 4096.0;
    double hsic = r3[0] - (2.0 / n) * r0[0] + (r1[0] * r2[0]) / (n * n);
    out[0] = (float)(-hsic / ((n - 1.0) * (n - 1.0)));
  }
}

extern "C" void kernel_launch(void* const* d_in, const int* in_sizes, int n_in,
                              void* d_out, int out_size, void* d_ws, size_t ws_size,
                              hipStream_t stream) {
  const float* W = (const float*)d_in[0];
  const float* G = (const float*)d_in[1];
  char* ws = (char*)d_ws;
  unsigned char* Wb = (unsigned char*)(ws + WB_OFF);
  unsigned char* Gb = (unsigned char*)(ws + GB_OFF);
  float* sqbW = (float*)(ws + SQBW_OFF);
  float* sqbG = (float*)(ws + SQBG_OFF);
  float* scs = (float*)(ws + SCS_OFF);
  double* ssp = (double*)(ws + SSP_OFF);
  float* PU = (float*)(ws + PU_OFF);
  float* PV = (float*)(ws + PV_OFF);
  double* PSL = (double*)(ws + PSL_OFF);
  double* fsl = (double*)(ws + FSL_OFF);

  hipMemsetAsync(ws + ZERO_BEG, 0, ZERO_END - ZERO_BEG, stream);

  prep_rows<<<2112, 256, 0, stream>>>(W, G, Wb, Gb, sqbW, sqbG, ssp, scs);
  gram_kernel<<<253, 512, 0, stream>>>(Wb, Gb, sqbW, sqbG, scs, ssp, PU, PV, PSL);
  finalize1<<<33, 128, 0, stream>>>(PU, PV, fsl);
  finalize2<<<1, 256, 0, stream>>>(PSL, fsl, (float*)d_out);
}

// Round 9
// 64.387 us; speedup vs baseline: 1.6064x; 1.0082x over previous
//
#include <hip/hip_runtime.h>
#include <stdint.h>

typedef __attribute__((ext_vector_type(4))) float f32x4;
typedef __attribute__((ext_vector_type(2))) unsigned int u32x2;

#define NROW 4096
#define DDIM 512
#define NT   22            // tiles per dim
#define TS   192
#define NPAD 4224

// ---------------- ws layout (bytes) ----------------
#define WB_OFF   0u          // fp8[4224*512] = 2162688
#define GB_OFF   2162688u    // fp8[4224*512]
#define SQBW_OFF 4325376u    // float[4224]
#define SQBG_OFF 4342272u    // float[4224]
#define SCS_OFF  4359168u    // float[32][512] (zeroed)
#define SSP_OFF  4424704u    // double[256]    (zeroed)
#define PU_OFF   4426752u    // float[22][22][192] = 371712 (fully written)
#define PV_OFF   4798464u    // float[22][22][192]
#define PSL_OFF  5170176u    // double[253]    (fully written)
#define ZERO_BEG SCS_OFF
#define ZERO_END (SSP_OFF + 2048u)

__device__ __forceinline__ void atomAddF64(double* p, double v) {
  __hip_atomic_fetch_add(p, v, __ATOMIC_RELAXED, __HIP_MEMORY_SCOPE_AGENT);
}
__device__ __forceinline__ void atomAddF32(float* p, float v) {
  __hip_atomic_fetch_add(p, v, __ATOMIC_RELAXED, __HIP_MEMORY_SCOPE_AGENT);
}

// ---- fp8 e4m3fn helpers (decode is format-exact; encode prefers HW cvt) ----
__device__ __forceinline__ float fp8dec(unsigned b) {
  unsigned e = (b >> 3) & 15u, m = b & 7u;
  float v = ldexpf((float)(e ? (m | 8u) : m), (int)e - 10 + (e == 0));
  return (b & 0x80u) ? -v : v;
}

__device__ __forceinline__ unsigned f2fp8_manual(float f) {
  unsigned u = __float_as_uint(f);
  unsigned s = (u >> 24) & 0x80u;
  float a = __uint_as_float(u & 0x7FFFFFFFu);
  if (a >= 448.f) return s | 0x7Eu;           // saturate to 448
  if (a >= 0.015625f) {                       // normal (>= 2^-6)
    unsigned au = __float_as_uint(a);
    au += 0x7FFFFu + ((au >> 20) & 1u);       // RNE into 3-bit mantissa
    unsigned e = (au >> 23) - 120u;           // bias 127 -> 7
    unsigned m = (au >> 20) & 7u;
    if (e >= 16u) return s | 0x7Eu;
    return s | (e << 3) | m;
  }
  int q = (int)rintf(a * 512.f);              // denormal: multiples of 2^-9
  return s | (unsigned)q;                     // q==8 -> min normal 2^-6
}

#if __has_builtin(__builtin_amdgcn_cvt_pk_fp8_f32)
__device__ __forceinline__ unsigned pack4_fp8(float x0, float x1, float x2, float x3) {
  unsigned p = __builtin_amdgcn_cvt_pk_fp8_f32(x0, x1, 0, false);
  p = __builtin_amdgcn_cvt_pk_fp8_f32(x2, x3, p, true);
  return p;
}
#else
__device__ __forceinline__ unsigned pack4_fp8(float x0, float x1, float x2, float x3) {
  return f2fp8_manual(x0) | (f2fp8_manual(x1) << 8) |
         (f2fp8_manual(x2) << 16) | (f2fp8_manual(x3) << 24);
}
#endif

__device__ __forceinline__ void gload16(const void* g, void* l) {
  __builtin_amdgcn_global_load_lds(
      (const __attribute__((address_space(1))) unsigned int*)g,
      (__attribute__((address_space(3))) unsigned int*)l, 16, 0, 0);
}

// ---- prep: fp32->fp8 e4m3 (+zero pad rows), fp8-consistent row sumsq, fused column sums
__global__ __launch_bounds__(256) void prep_rows(
    const float* __restrict__ W, const float* __restrict__ G,
    unsigned char* __restrict__ Wb, unsigned char* __restrict__ Gb,
    float* __restrict__ sqbW, float* __restrict__ sqbG,
    double* __restrict__ ssp, float* __restrict__ scs)
{
  __shared__ float cols[4][512];
  const int bid = blockIdx.x;
  const int w = threadIdx.x >> 6;
  const int l = threadIdx.x & 63;

  if (bid >= 2048) {                       // pad-row zeroing blocks
    const int pr = (bid - 2048) * 4 + w;   // 0..255
    const bool isG = pr >= 128;
    const int row = NROW + (pr & 127);     // 4096..4223
    unsigned char* dst = (isG ? Gb : Wb) + (size_t)row * DDIM;
    *(u32x2*)(dst + l * 8) = (u32x2){0u, 0u};
    if (l == 0) (isG ? sqbG : sqbW)[row] = 0.f;
    return;
  }

  const int row = bid * 4 + w;             // 0..8191
  const float* src; unsigned char* dst; float* sqb; int r;
  if (row < NROW) { src = W + (size_t)row * DDIM; dst = Wb + (size_t)row * DDIM; sqb = sqbW; r = row; }
  else            { src = G + (size_t)(row - NROW) * DDIM; dst = Gb + (size_t)(row - NROW) * DDIM; sqb = sqbG; r = row - NROW; }
  const f32x4 a = *(const f32x4*)(src + l * 8);
  const f32x4 b = *(const f32x4*)(src + l * 8 + 4);

  const unsigned p0 = pack4_fp8(a[0], a[1], a[2], a[3]);
  const unsigned p1 = pack4_fp8(b[0], b[1], b[2], b[3]);
  *(u32x2*)(dst + l * 8) = (u32x2){p0, p1};

  float s32 = 0.f, sb = 0.f;
  #pragma unroll
  for (int j = 0; j < 4; ++j) { s32 += a[j] * a[j]; s32 += b[j] * b[j]; }
  #pragma unroll
  for (int j = 0; j < 4; ++j) {
    float xa = fp8dec((p0 >> (8 * j)) & 0xFFu);
    float xb = fp8dec((p1 >> (8 * j)) & 0xFFu);
    sb += xa * xa + xb * xb;
  }

  // fused column sums (fp32 source values); f32 atomics are L2-native (cheap)
  *(f32x4*)&cols[w][l * 8] = a;
  *(f32x4*)&cols[w][l * 8 + 4] = b;
  __syncthreads();
  for (int c = threadIdx.x; c < 512; c += 256)
    atomAddF32(&scs[(bid & 31) * 512 + c],
               cols[0][c] + cols[1][c] + cols[2][c] + cols[3][c]);

  #pragma unroll
  for (int off = 32; off > 0; off >>= 1) { s32 += __shfl_down(s32, off); sb += __shfl_down(sb, off); }
  if (l == 0) { sqb[r] = sb; atomAddF64(&ssp[bid & 255], (double)s32); }
}

// ---- stage one K-half (256 B) of A (rows i0..) and B (rows j0..) of one matrix:
// 2 x 48 KiB panels. Linear LDS dest; source 16B-slot pre-swizzled s^((row>>1)&7)
// (inverse of the read-side 8B XOR j8^(row&14) — rule #21, both sides).
__device__ __forceinline__ void do_stage(
    const unsigned char* __restrict__ mat, int i0, int j0, int kh,
    int tid, unsigned char* __restrict__ lds)
{
  #pragma unroll
  for (int q = 0; q < 6; ++q) {
    const int slot = q * 512 + tid;        // 0..3071 (16B each; 16 per 256B row)
    const int row = slot >> 4;             // 0..191
    const int sp = (slot & 15) ^ ((row >> 1) & 7);
    gload16(mat + (size_t)(i0 + row) * 512 + kh + sp * 16, lds + slot * 16);
    gload16(mat + (size_t)(j0 + row) * 512 + kh + sp * 16, lds + 49152 + slot * 16);
  }
}

// ---- one K=256 compute pass: 8 q-chunks x 18 MFMA. b64 reads, conflict-free swizzle.
__device__ __forceinline__ void do_compute(
    const unsigned char* __restrict__ lds,
    int wr, int wc, int lr, int g, f32x4 acc[6][3])
{
  #pragma unroll
  for (int q = 0; q < 8; ++q) {
    long long a[6], b[3];
    #pragma unroll
    for (int m = 0; m < 6; ++m) {
      const int row = wr * 96 + m * 16 + lr;
      a[m] = *(const long long*)(lds + row * 256 + ((((q << 2) | g) ^ (row & 14)) << 3));
    }
    #pragma unroll
    for (int n = 0; n < 3; ++n) {
      const int row = wc * 48 + n * 16 + lr;
      b[n] = *(const long long*)(lds + 49152 + row * 256 + ((((q << 2) | g) ^ (row & 14)) << 3));
    }
    __builtin_amdgcn_s_setprio(1);
    #pragma unroll
    for (int m = 0; m < 6; ++m)
      #pragma unroll
      for (int n = 0; n < 3; ++n)
        acc[m][n] = __builtin_amdgcn_mfma_f32_16x16x32_fp8_fp8(a[m], b[n], acc[m][n], 0, 0, 0);
    __builtin_amdgcn_s_setprio(0);
  }
}

// ---- main fused kernel: 4 big stages (W-k0, W-k1, G-k0, G-k1), 4 drains total
__global__ __launch_bounds__(512, 1) void gram_kernel(
    const unsigned char* __restrict__ Wb, const unsigned char* __restrict__ Gb,
    const float* __restrict__ sqbW, const float* __restrict__ sqbG,
    const float* __restrict__ scs, const double* __restrict__ ssp,
    float* __restrict__ PU, float* __restrict__ PV, double* __restrict__ PSL)
{
  __shared__ __align__(16) unsigned char lds[98304];   // A|B panels, 48KB each
  __shared__ float L[768];   // rowW|rowG|colW|colG reduction arrays
  __shared__ double pred[8], pred2[8];
  __shared__ float sS4;

  // T1: bijective XCD-chunked swizzle (nwg=253: q=31, r=5)
  const int orig = blockIdx.x;
  const int xcd = orig & 7;
  const int idx = orig >> 3;
  const int swz = (xcd < 5 ? xcd * 32 : 5 * 32 + (xcd - 5) * 31) + idx;

  // decode upper-triangular tile index: 0 <= bi <= bj < 22
  int t = swz;
  int bi = 0;
  while (t >= NT - bi) { t -= NT - bi; ++bi; }
  const int bj = bi + t;
  const bool offdiag = (bi != bj);

  const int tid = threadIdx.x;
  const int lane = tid & 63;
  const int wid = tid >> 6;
  const int wr = wid >> 2;      // 0..1  (96-row half)
  const int wc = wid & 3;       // 0..3  (48-col quarter)
  const int i0 = bi * TS;
  const int j0 = bj * TS;
  const int g = lane >> 4;
  const int lr = lane & 15;

  // zero reduction arrays completely (512 threads, 768 slots: two strided passes)
  L[tid] = 0.f;
  if (tid < 256) L[512 + tid] = 0.f;

  f32x4 accW[6][3], accG[6][3];
  #pragma unroll
  for (int m = 0; m < 6; ++m)
    #pragma unroll
    for (int n = 0; n < 3; ++n) { accW[m][n] = (f32x4)0.0f; accG[m][n] = (f32x4)0.0f; }

  do_stage(Wb, i0, j0, 0, tid, lds);   __syncthreads();
  do_compute(lds, wr, wc, lr, g, accW); __syncthreads();
  do_stage(Wb, i0, j0, 256, tid, lds); __syncthreads();
  do_compute(lds, wr, wc, lr, g, accW); __syncthreads();
  do_stage(Gb, i0, j0, 0, tid, lds);   __syncthreads();
  do_compute(lds, wr, wc, lr, g, accG); __syncthreads();
  do_stage(Gb, i0, j0, 256, tid, lds); __syncthreads();
  do_compute(lds, wr, wc, lr, g, accG); __syncthreads();

  // ---- folded bwk: bandwidth scale computed redundantly per block ----
  {
    float cs = 0.f;
    #pragma unroll 8
    for (int p = 0; p < 32; ++p) cs += scs[p * 512 + tid];
    double p1 = (double)cs * (double)cs;
    double p2 = (tid < 256) ? ssp[tid] : 0.0;
    #pragma unroll
    for (int off = 32; off > 0; off >>= 1) {
      p1 += __shfl_xor(p1, off);
      p2 += __shfl_xor(p2, off);
    }
    if (lane == 0) { pred[wid] = p1; pred2[wid] = p2; }
    __syncthreads();
    if (tid == 0) {
      double s2 = 0.0, ss = 0.0;
      #pragma unroll
      for (int k = 0; k < 8; ++k) { s2 += pred[k]; ss += pred2[k]; }
      double sum_d2 = 2.0 * 8192.0 * ss - 2.0 * s2;
      double bw = sum_d2 / (8192.0 * 8191.0) / 4.0;
      sS4 = (float)(1.4426950408889634 / (bw * 16.0));
    }
    __syncthreads();
  }
  const float s4 = sS4;

  // ---- epilogue: kernel values (registers only) ----
  float rjW[3], rjG[3], mjf[3];
  #pragma unroll
  for (int n = 0; n < 3; ++n) {
    const int j = j0 + wc * 48 + n * 16 + lr;
    rjW[n] = sqbW[j]; rjG[n] = sqbG[j];
    mjf[n] = (j < NROW) ? 1.f : 0.f;
  }

  float csW[3] = {0.f, 0.f, 0.f}, csG[3] = {0.f, 0.f, 0.f};
  float rsW[6][4], rsG[6][4];
  double p_loc = 0.0;

  #pragma unroll
  for (int m = 0; m < 6; ++m) {
    const int ib = i0 + wr * 96 + m * 16 + g * 4;
    float riW[4], riG[4], mif[4];
    #pragma unroll
    for (int e = 0; e < 4; ++e) {
      riW[e] = sqbW[ib + e]; riG[e] = sqbG[ib + e];
      mif[e] = (ib + e < NROW) ? 1.f : 0.f;
    }
    #pragma unroll
    for (int e = 0; e < 4; ++e) { rsW[m][e] = 0.f; rsG[m][e] = 0.f; }
    #pragma unroll
    for (int n = 0; n < 3; ++n) {
      #pragma unroll
      for (int e = 0; e < 4; ++e) {
        const float mk = mif[e] * mjf[n];
        float d2w = fmaxf(riW[e] + rjW[n] - 2.f * accW[m][n][e], 0.f);
        float yw = exp2f(-d2w * s4);
        float yw2 = yw * yw, yw4 = yw2 * yw2, yw8 = yw4 * yw4, yw16 = yw8 * yw8;
        float kw = (yw + yw2 + yw4 + yw8 + yw16) * mk;
        float d2g = fmaxf(riG[e] + rjG[n] - 2.f * accG[m][n][e], 0.f);
        float yg = exp2f(-d2g * s4);
        float yg2 = yg * yg, yg4 = yg2 * yg2, yg8 = yg4 * yg4, yg16 = yg8 * yg8;
        float kg = (yg + yg2 + yg4 + yg8 + yg16) * mk;
        p_loc += (double)(kw * kg);
        rsW[m][e] += kw; rsG[m][e] += kg;
        csW[n] += kw; csG[n] += kg;
      }
    }
  }

  // row sums -> LDS (butterfly over the 16 column-lanes, then 4-way LDS atomic)
  #pragma unroll
  for (int m = 0; m < 6; ++m)
    #pragma unroll
    for (int e = 0; e < 4; ++e) {
      float x = rsW[m][e], y = rsG[m][e];
      x += __shfl_xor(x, 1); x += __shfl_xor(x, 2); x += __shfl_xor(x, 4); x += __shfl_xor(x, 8);
      y += __shfl_xor(y, 1); y += __shfl_xor(y, 2); y += __shfl_xor(y, 4); y += __shfl_xor(y, 8);
      if (lr == 0) {
        const int rloc = wr * 96 + m * 16 + g * 4 + e;   // 0..191
        atomicAdd(&L[rloc], x);
        atomicAdd(&L[192 + rloc], y);
      }
    }

  // col sums -> LDS (butterfly over g-groups, then 2-way LDS atomic)
  if (offdiag) {
    #pragma unroll
    for (int n = 0; n < 3; ++n) {
      float x = csW[n], y = csG[n];
      x += __shfl_xor(x, 16); x += __shfl_xor(x, 32);
      y += __shfl_xor(y, 16); y += __shfl_xor(y, 32);
      if (g == 0) {
        const int cloc = wc * 48 + n * 16 + lr;          // 0..191
        atomicAdd(&L[384 + cloc], x);
        atomicAdd(&L[576 + cloc], y);
      }
    }
  }

  __syncthreads();

  // plain coalesced partial stores (no global atomics):
  // row-part of tile (bi,bj) -> slot (bi,bj); col-part -> (bj,bi). Full coverage.
  if (tid < 192) {
    PU[(bi * NT + bj) * 192 + tid] = L[tid];
    PV[(bi * NT + bj) * 192 + tid] = L[192 + tid];
    if (offdiag) {
      PU[(bj * NT + bi) * 192 + tid] = L[384 + tid];
      PV[(bj * NT + bi) * 192 + tid] = L[576 + tid];
    }
  }

  // P: wave butterfly, block sum, ONE plain f64 store per tile
  #pragma unroll
  for (int off = 32; off > 0; off >>= 1) p_loc += __shfl_xor(p_loc, off);
  if (lane == 0) pred[wid] = p_loc;
  __syncthreads();
  if (tid == 0) {
    double ps = 0.0;
    #pragma unroll
    for (int k = 0; k < 8; ++k) ps += pred[k];
    PSL[swz] = offdiag ? 2.0 * ps : ps;
  }
}

// ---- finalize (single launch): u,v from partials; loss
__global__ __launch_bounds__(1024) void finalize(
    const float* __restrict__ PU, const float* __restrict__ PV,
    const double* __restrict__ PSL, float* __restrict__ out)
{
  __shared__ double r0[1024], r1[1024], r2[1024], r3[1024];
  const int t = threadIdx.x;
  double uv = 0.0, su = 0.0, sv = 0.0, pp = 0.0;
  for (int i = t; i < NPAD; i += 1024) {
    const int b = i / 192, ii = i - b * 192;
    double uu = 0.0, vv = 0.0;
    #pragma unroll
    for (int k = 0; k < NT; ++k) {
      uu += (double)PU[(b * NT + k) * 192 + ii];
      vv += (double)PV[(b * NT + k) * 192 + ii];
    }
    uv += uu * vv; su += uu; sv += vv;
  }
  if (t < 253) pp = PSL[t];
  r0[t] = uv; r1[t] = su; r2[t] = sv; r3[t] = pp;
  __syncthreads();
  for (int k = 512; k > 0; k >>= 1) {
    if (t < k) { r0[t] += r0[t + k]; r1[t] += r1[t + k]; r2[t] += r2[t + k]; r3[t] += r3[t + k]; }
    __syncthreads();
  }
  if (t == 0) {
    const double n = 4096.0;
    double hsic = r3[0] - (2.0 / n) * r0[0] + (r1[0] * r2[0]) / (n * n);
    out[0] = (float)(-hsic / ((n - 1.0) * (n - 1.0)));
  }
}

extern "C" void kernel_launch(void* const* d_in, const int* in_sizes, int n_in,
                              void* d_out, int out_size, void* d_ws, size_t ws_size,
                              hipStream_t stream) {
  const float* W = (const float*)d_in[0];
  const float* G = (const float*)d_in[1];
  char* ws = (char*)d_ws;
  unsigned char* Wb = (unsigned char*)(ws + WB_OFF);
  unsigned char* Gb = (unsigned char*)(ws + GB_OFF);
  float* sqbW = (float*)(ws + SQBW_OFF);
  float* sqbG = (float*)(ws + SQBG_OFF);
  float* scs = (float*)(ws + SCS_OFF);
  double* ssp = (double*)(ws + SSP_OFF);
  float* PU = (float*)(ws + PU_OFF);
  float* PV = (float*)(ws + PV_OFF);
  double* PSL = (double*)(ws + PSL_OFF);

  hipMemsetAsync(ws + ZERO_BEG, 0, ZERO_END - ZERO_BEG, stream);

  prep_rows<<<2112, 256, 0, stream>>>(W, G, Wb, Gb, sqbW, sqbG, ssp, scs);
  gram_kernel<<<253, 512, 0, stream>>>(Wb, Gb, sqbW, sqbG, scs, ssp, PU, PV, PSL);
  finalize<<<1, 1024, 0, stream>>>(PU, PV, PSL, (float*)d_out);
}